// Round 9
// baseline (223.711 us; speedup 1.0000x reference)
//
#include <hip/hip_runtime.h>
#include <hip/hip_bf16.h>
#include <math.h>

#define B_  4
#define S_  2048
#define D_  512
#define H_  8
#define DK_ 64
#define BS_ (B_*S_)

using bf16x8 = __attribute__((ext_vector_type(8))) short;
using f32x4  = __attribute__((ext_vector_type(4))) float;
using f32x16 = __attribute__((ext_vector_type(16))) float;

typedef const __attribute__((address_space(1))) unsigned int gu32;
typedef __attribute__((address_space(3))) unsigned int lu32;

static __device__ inline float bf16f(unsigned short u) {
  union { unsigned u32; float f; } x; x.u32 = (unsigned)u << 16; return x.f;
}
// HW packed f32->bf16 (RNE), 1 VALU op for 2 values
static __device__ inline unsigned pk2(float a, float b) {
  unsigned r;
  asm("v_cvt_pk_bf16_f32 %0, %1, %2" : "=v"(r) : "v"(a), "v"(b));
  return r;
}
static __device__ inline float ex2(float a) {
  return __builtin_amdgcn_exp2f(a);   // raw v_exp_f32
}

// ---------------------------------------------------------------------------
// W prep: for each of the 3 weight matrices, produce W^T bf16 planes
// [n][k] (hi, and lo residual where needed). Values are bit-identical to the
// old in-GEMM conversion (same pk2 RNE, same residual formula).
// grid = 192: blocks 0..63 -> W_fk (hi+lo), 64..127 -> W0 (hi), 128..191 ->
// Wout (hi+lo). Within a matrix: 8x8 tiles of 64x64.
// ---------------------------------------------------------------------------
__global__ __launch_bounds__(256) void wprep_kernel(
    const float* __restrict__ Wfk, const float* __restrict__ W0,
    const float* __restrict__ Wout,
    unsigned short* __restrict__ t0h, unsigned short* __restrict__ t0l,
    unsigned short* __restrict__ t1h,
    unsigned short* __restrict__ t2h, unsigned short* __restrict__ t2l) {
  const int bid = blockIdx.x;
  const int mi = bid >> 6, t = bid & 63;
  const float* W = (mi == 0) ? Wfk : (mi == 1) ? W0 : Wout;
  unsigned short* th = (mi == 0) ? t0h : (mi == 1) ? t1h : t2h;
  unsigned short* tl = (mi == 0) ? t0l : (mi == 1) ? nullptr : t2l;
  const int kt = t >> 3, nt = t & 7;
  const int tid = threadIdx.x;

  __shared__ float Ts[64][68];
  {  // load 64(k) x 64(n) tile, coalesced along n
    const int r = tid >> 2, c = (tid & 3) * 16;
    const float* src = W + (size_t)(kt * 64 + r) * D_ + nt * 64 + c;
#pragma unroll
    for (int i = 0; i < 4; ++i)
      *(float4*)&Ts[r][c + i * 4] = *(const float4*)(src + i * 4);
  }
  __syncthreads();
  {  // write W^T rows: out row n, 16 k-values per thread
    const int n = tid >> 2, kc = (tid & 3) * 16;
    float v[16];
#pragma unroll
    for (int i = 0; i < 16; ++i) v[i] = Ts[kc + i][n];
    unsigned h[8], l[8];
#pragma unroll
    for (int p = 0; p < 8; ++p) {
      h[p] = pk2(v[2 * p], v[2 * p + 1]);
      if (tl)
        l[p] = pk2(v[2 * p] - bf16f((unsigned short)(h[p] & 0xffff)),
                   v[2 * p + 1] - bf16f((unsigned short)(h[p] >> 16)));
    }
    unsigned short* dh = th + (size_t)(nt * 64 + n) * D_ + kt * 64 + kc;
    uint4 u0; u0.x = h[0]; u0.y = h[1]; u0.z = h[2]; u0.w = h[3];
    uint4 u1; u1.x = h[4]; u1.y = h[5]; u1.z = h[6]; u1.w = h[7];
    *(uint4*)dh = u0; *(uint4*)(dh + 8) = u1;
    if (tl) {
      unsigned short* dl = tl + (size_t)(nt * 64 + n) * D_ + kt * 64 + kc;
      uint4 w0; w0.x = l[0]; w0.y = l[1]; w0.z = l[2]; w0.w = l[3];
      uint4 w1; w1.x = l[4]; w1.y = l[5]; w1.z = l[6]; w1.w = l[7];
      *(uint4*)dl = w0; *(uint4*)(dl + 8) = w1;
    }
  }
}

// ---------------------------------------------------------------------------
// MFMA GEMM v3: C = A @ W + bias, bf16 split-precision.
// W comes from pre-transposed bf16 planes (contiguous uint4 staging).
// A: APLANES=0 -> f32 rows, converted in-kernel (unchanged math);
//    APLANES=1 -> pre-split bf16 hi/lo planes (pure uint4 staging).
// Register-prefetch pipeline: tile t+1 global loads issue right after the
// LDS-write barrier, hiding latency under tile t's MFMAs.
// OUTMODE: 0 = f32 row-major, 2 = bf16 V^T [b][n][s].
// ---------------------------------------------------------------------------
template <int SPLIT, int APLANES, int OUTMODE>
__global__ __launch_bounds__(256) void gemm_v3_kernel(
    const float* __restrict__ A,
    const unsigned short* __restrict__ Aph, const unsigned short* __restrict__ Apl,
    const unsigned short* __restrict__ Wth, const unsigned short* __restrict__ Wtl,
    const float* __restrict__ bias, void* __restrict__ Cv) {
  const int bn = blockIdx.x;      // 8
  const int bm = blockIdx.y;      // 64
  const int tid = threadIdx.x;
  const int wv = tid >> 6, lane = tid & 63;
  const int c = lane & 15, g = lane >> 4;

  __shared__ unsigned short As[SPLIT + 1][128][72];
  __shared__ unsigned short Wt[SPLIT + 1][64][72];

  f32x4 acc[2][4];
#pragma unroll
  for (int rt = 0; rt < 2; ++rt)
#pragma unroll
    for (int ds = 0; ds < 4; ++ds) acc[rt][ds] = f32x4{0.f, 0.f, 0.f, 0.f};

  const int arow = tid >> 1, ahh = (tid & 1) * 32;
  const int wn = tid & 63, wkg = (tid >> 6) * 16;

  // prefetch registers
  float afr[32];
  uint4 ahr[4], alr[4];
  uint4 whr[2], wlr[2];

  auto LOADT = [&](int k0) {
    if constexpr (!APLANES) {
      const float* ag = A + (size_t)(bm * 128 + arow) * D_ + k0 + ahh;
#pragma unroll
      for (int i = 0; i < 8; ++i) *(float4*)&afr[i * 4] = *(const float4*)(ag + i * 4);
    } else {
      const unsigned short* agh = Aph + (size_t)(bm * 128 + arow) * D_ + k0 + ahh;
#pragma unroll
      for (int i = 0; i < 4; ++i) ahr[i] = *(const uint4*)(agh + i * 8);
      const unsigned short* agl = Apl + (size_t)(bm * 128 + arow) * D_ + k0 + ahh;
#pragma unroll
      for (int i = 0; i < 4; ++i) alr[i] = *(const uint4*)(agl + i * 8);
    }
    const unsigned short* wgh = Wth + (size_t)(bn * 64 + wn) * D_ + k0 + wkg;
    whr[0] = *(const uint4*)wgh; whr[1] = *(const uint4*)(wgh + 8);
    if constexpr (SPLIT) {
      const unsigned short* wgl = Wtl + (size_t)(bn * 64 + wn) * D_ + k0 + wkg;
      wlr[0] = *(const uint4*)wgl; wlr[1] = *(const uint4*)(wgl + 8);
    }
  };
  auto STORET = [&]() {
    if constexpr (!APLANES) {
#pragma unroll
      for (int grp = 0; grp < 4; ++grp) {
        unsigned h[4], l[4];
#pragma unroll
        for (int p = 0; p < 4; ++p) {
          float f0 = afr[grp * 8 + p * 2], f1 = afr[grp * 8 + p * 2 + 1];
          h[p] = pk2(f0, f1);
          if constexpr (SPLIT)
            l[p] = pk2(f0 - bf16f((unsigned short)(h[p] & 0xffff)),
                       f1 - bf16f((unsigned short)(h[p] >> 16)));
        }
        uint4 uh; uh.x = h[0]; uh.y = h[1]; uh.z = h[2]; uh.w = h[3];
        *(uint4*)&As[0][arow][ahh + grp * 8] = uh;
        if constexpr (SPLIT) {
          uint4 ul; ul.x = l[0]; ul.y = l[1]; ul.z = l[2]; ul.w = l[3];
          *(uint4*)&As[1][arow][ahh + grp * 8] = ul;
        }
      }
    } else {
#pragma unroll
      for (int i = 0; i < 4; ++i) {
        *(uint4*)&As[0][arow][ahh + i * 8] = ahr[i];
        *(uint4*)&As[1][arow][ahh + i * 8] = alr[i];
      }
    }
    *(uint4*)&Wt[0][wn][wkg] = whr[0];
    *(uint4*)&Wt[0][wn][wkg + 8] = whr[1];
    if constexpr (SPLIT) {
      *(uint4*)&Wt[1][wn][wkg] = wlr[0];
      *(uint4*)&Wt[1][wn][wkg + 8] = wlr[1];
    }
  };

  LOADT(0);
  for (int k0 = 0; k0 < D_; k0 += 64) {
    __syncthreads();        // prev MFMA done reading LDS
    STORET();
    __syncthreads();
    if (k0 + 64 < D_) LOADT(k0 + 64);   // hides under MFMA below

#pragma unroll
    for (int ksub = 0; ksub < 2; ++ksub) {
      bf16x8 bh[2], bl[2];
#pragma unroll
      for (int rt = 0; rt < 2; ++rt) {
        bh[rt] = *(const bf16x8*)&As[0][wv * 32 + rt * 16 + c][ksub * 32 + g * 8];
        if constexpr (SPLIT)
          bl[rt] = *(const bf16x8*)&As[1][wv * 32 + rt * 16 + c][ksub * 32 + g * 8];
      }
#pragma unroll
      for (int ds = 0; ds < 4; ++ds) {
        bf16x8 ah_ = *(const bf16x8*)&Wt[0][ds * 16 + c][ksub * 32 + g * 8];
#pragma unroll
        for (int rt = 0; rt < 2; ++rt)
          acc[rt][ds] = __builtin_amdgcn_mfma_f32_16x16x32_bf16(ah_, bh[rt], acc[rt][ds], 0, 0, 0);
        if constexpr (SPLIT) {
          bf16x8 al_ = *(const bf16x8*)&Wt[1][ds * 16 + c][ksub * 32 + g * 8];
#pragma unroll
          for (int rt = 0; rt < 2; ++rt) {
            acc[rt][ds] = __builtin_amdgcn_mfma_f32_16x16x32_bf16(ah_, bl[rt], acc[rt][ds], 0, 0, 0);
            acc[rt][ds] = __builtin_amdgcn_mfma_f32_16x16x32_bf16(al_, bh[rt], acc[rt][ds], 0, 0, 0);
          }
        }
      }
    }
  }

#pragma unroll
  for (int rt = 0; rt < 2; ++rt) {
    const size_t m = (size_t)bm * 128 + wv * 32 + rt * 16 + c;
#pragma unroll
    for (int ds = 0; ds < 4; ++ds) {
      const int n = bn * 64 + ds * 16 + 4 * g;
      float4 bv = *(const float4*)&bias[n];
      float o0 = acc[rt][ds][0] + bv.x, o1 = acc[rt][ds][1] + bv.y;
      float o2 = acc[rt][ds][2] + bv.z, o3 = acc[rt][ds][3] + bv.w;
      if constexpr (OUTMODE == 2) {
        // V^T: [b][n][s]; b = m>>11, s = m&2047 (block never crosses batch)
        const unsigned u01 = pk2(o0, o1), u23 = pk2(o2, o3);
        unsigned short* base =
            (unsigned short*)Cv + ((size_t)(m >> 11) * D_ + n) * (size_t)S_ + (m & 2047);
        base[0]      = (unsigned short)u01;
        base[S_]     = (unsigned short)(u01 >> 16);
        base[2 * S_] = (unsigned short)u23;
        base[3 * S_] = (unsigned short)(u23 >> 16);
      } else {
        float4 o; o.x = o0; o.y = o1; o.z = o2; o.w = o3;
        *(float4*)((float*)Cv + m * D_ + n) = o;
      }
    }
  }
}

// ---------------------------------------------------------------------------
// Causal local-window (L=5) softmax pooling; f32 in, bf16 out (scaled).
// ---------------------------------------------------------------------------
__global__ __launch_bounds__(256) void local_pool_kernel(
    const float* __restrict__ x, unsigned short* __restrict__ out,
    float oscale) {
  const int gtid = blockIdx.x * 256 + threadIdx.x;
  const int wave = gtid >> 6;
  const int lane = gtid & 63;
  if (wave >= BS_) return;
  const int b = wave / S_, s = wave % S_;
  const float* xrow = x + ((size_t)b * S_ + s) * D_;
  const int d0 = lane * 8;
  float xi[8];
  *(float4*)&xi[0] = *(const float4*)&xrow[d0];
  *(float4*)&xi[4] = *(const float4*)&xrow[d0 + 4];
  float win[5][8];
  float sc[5];
#pragma unroll
  for (int j = 0; j < 5; ++j) {
    int src = s - 4 + j;
    float part = 0.f;
    if (src >= 0) {
      const float* wr = x + ((size_t)b * S_ + src) * D_;
      *(float4*)&win[j][0] = *(const float4*)&wr[d0];
      *(float4*)&win[j][4] = *(const float4*)&wr[d0 + 4];
#pragma unroll
      for (int t = 0; t < 8; ++t) part += xi[t] * win[j][t];
    } else {
#pragma unroll
      for (int t = 0; t < 8; ++t) win[j][t] = 0.f;
    }
    sc[j] = part;
  }
#pragma unroll
  for (int off = 1; off < 64; off <<= 1) {
#pragma unroll
    for (int j = 0; j < 5; ++j) sc[j] += __shfl_xor(sc[j], off, 64);
  }
  const float scale = 0.04419417382415922f;  // 1/sqrt(512)
  float m = sc[0] * scale;
#pragma unroll
  for (int j = 1; j < 5; ++j) m = fmaxf(m, sc[j] * scale);
  float w[5], lsum = 0.f;
#pragma unroll
  for (int j = 0; j < 5; ++j) { w[j] = expf(sc[j] * scale - m); lsum += w[j]; }
  const float inv = oscale / lsum;
  float o[8] = {};
#pragma unroll
  for (int j = 0; j < 5; ++j)
#pragma unroll
    for (int t = 0; t < 8; ++t) o[t] += w[j] * win[j][t];
  unsigned short* orow = out + ((size_t)b * S_ + s) * D_;
  uint4 pk;
  pk.x = pk2(o[0] * inv, o[1] * inv);
  pk.y = pk2(o[2] * inv, o[3] * inv);
  pk.z = pk2(o[4] * inv, o[5] * inv);
  pk.w = pk2(o[6] * inv, o[7] * inv);
  *(uint4*)&orow[d0] = pk;
}

// ---------------------------------------------------------------------------
// 32x32x16 MFMA flash attention, 2-way KV-split, double-buffered async LDS.
// Unchanged from round 8 except the epilogue: output is written as bf16
// hi/lo planes (xh = bf16(x), xl = bf16(x - bf16(x))) -- bit-identical to
// the conversion the out-GEMM used to do in-kernel, which now reads planes.
// ---------------------------------------------------------------------------
__global__ __launch_bounds__(256, 2) void attn_mfma32_kernel(
    const unsigned short* __restrict__ q, const unsigned short* __restrict__ k,
    const unsigned short* __restrict__ vt,
    unsigned short* __restrict__ xh, unsigned short* __restrict__ xl) {
  const int bid = (blockIdx.x & 7) * 128 + (blockIdx.x >> 3);  // XCD swizzle
  const int qb = bid & 31;             // 64-row q-block
  const int h  = (bid >> 5) & 7;
  const int b  = bid >> 8;
  const int tid = threadIdx.x;
  const int w = tid >> 6, l = tid & 63;
  const int ql = l & 31, hi = l >> 5;
  const int wq = w & 1, wh = w >> 1;

  // [buf][0=K,1=V][half][64x64]
  __shared__ __align__(16) unsigned short L[2][2][2][4096];

  bf16x8 Qf[4];
  {
    const unsigned short* qg =
        q + ((size_t)b * S_ + qb * 64 + wq * 32 + ql) * D_ + h * 64 + hi * 8;
#pragma unroll
    for (int f = 0; f < 4; ++f) Qf[f] = *(const bf16x8*)(qg + f * 16);
  }

  f32x16 accO[2] = {};           // O^T: [d-tile 32][q]
  float m = -INFINITY, lsum = 0.f;

  const int lr8 = l >> 3, lc = l & 7;
  const unsigned short* kg =
      k + ((size_t)b * S_ + wh * 1024 + wq * 32 + lr8) * D_ + h * 64 + ((lc ^ lr8) << 3);
  const unsigned short* vg =
      vt + ((size_t)b * D_ + h * 64 + wq * 32 + lr8) * (size_t)S_ + wh * 1024 + ((lc ^ lr8) << 3);

  auto ISSUE = [&](int t, int bf) {
    const unsigned short* kp = kg + (size_t)t * 64 * D_;
    const unsigned short* vp = vg + t * 64;
    char* dk = (char*)&L[bf][0][wh][0] + wq * 4096;
    char* dv = (char*)&L[bf][1][wh][0] + wq * 4096;
#pragma unroll
    for (int j = 0; j < 4; ++j) {
      __builtin_amdgcn_global_load_lds((gu32*)(kp + (size_t)j * 8 * D_),
                                       (lu32*)(dk + j * 1024), 16, 0, 0);
      __builtin_amdgcn_global_load_lds((gu32*)(vp + (size_t)j * 8 * S_),
                                       (lu32*)(dv + j * 1024), 16, 0, 0);
    }
  };

  ISSUE(0, 0);
  asm volatile("s_waitcnt vmcnt(0)" ::: "memory");
  __builtin_amdgcn_s_barrier();
  __builtin_amdgcn_sched_barrier(0);

  int cur = 0;
  for (int kt = 0; kt < 16; ++kt) {
    if (kt + 1 < 16) ISSUE(kt + 1, cur ^ 1);   // lands under this tile's compute
    __builtin_amdgcn_sched_barrier(0);
    const char* KsB = (const char*)&L[cur][0][wh][0];
    const char* VtB = (const char*)&L[cur][1][wh][0];

    // ---- QK^T: two 32-key subtiles ----
    f32x16 sA = {}, sB = {};
    __builtin_amdgcn_s_setprio(1);
#pragma unroll
    for (int f = 0; f < 4; ++f) {
      bf16x8 a0 = *(const bf16x8*)(KsB + ((ql * 128 + f * 32 + hi * 16) ^ ((ql & 7) << 4)));
      bf16x8 a1 = *(const bf16x8*)(KsB + (((ql + 32) * 128 + f * 32 + hi * 16) ^ ((ql & 7) << 4)));
      sA = __builtin_amdgcn_mfma_f32_32x32x16_bf16(a0, Qf[f], sA, 0, 0, 0);
      sB = __builtin_amdgcn_mfma_f32_32x32x16_bf16(a1, Qf[f], sB, 0, 0, 0);
    }
    __builtin_amdgcn_s_setprio(0);

    // ---- tree max, defer-max THR=10 ----
    float mx[8];
#pragma unroll
    for (int r = 0; r < 8; ++r)
      mx[r] = fmaxf(fmaxf(sA[r], sA[r + 8]), fmaxf(sB[r], sB[r + 8]));
    mx[0] = fmaxf(mx[0], mx[4]); mx[1] = fmaxf(mx[1], mx[5]);
    mx[2] = fmaxf(mx[2], mx[6]); mx[3] = fmaxf(mx[3], mx[7]);
    mx[0] = fmaxf(fmaxf(mx[0], mx[1]), fmaxf(mx[2], mx[3]));
    const float mt = fmaxf(mx[0], __shfl_xor(mx[0], 32, 64));
    if (!__all(mt <= m + 10.0f)) {
      const float mn = fmaxf(m, mt);
      const float corr = ex2(m - mn);
      m = mn;
      lsum *= corr;
#pragma unroll
      for (int dt = 0; dt < 2; ++dt)
#pragma unroll
        for (int r = 0; r < 16; ++r) accO[dt][r] *= corr;
    }

    // ---- fused exp2 -> pack -> pairwise sum ----
    unsigned WA[8], WB[8];
    float s0 = 0.f, s1 = 0.f, s2 = 0.f, s3 = 0.f;
#pragma unroll
    for (int t = 0; t < 4; ++t) {
      float a0 = ex2(sA[4 * t + 0] - m), a1 = ex2(sA[4 * t + 1] - m);
      float a2 = ex2(sA[4 * t + 2] - m), a3 = ex2(sA[4 * t + 3] - m);
      WA[2 * t] = pk2(a0, a1); WA[2 * t + 1] = pk2(a2, a3);
      s0 += a0 + a1; s1 += a2 + a3;
      float b0 = ex2(sB[4 * t + 0] - m), b1 = ex2(sB[4 * t + 1] - m);
      float b2 = ex2(sB[4 * t + 2] - m), b3 = ex2(sB[4 * t + 3] - m);
      WB[2 * t] = pk2(b0, b1); WB[2 * t + 1] = pk2(b2, b3);
      s2 += b0 + b1; s3 += b2 + b3;
    }
    lsum += (s0 + s1) + (s2 + s3);

    // ---- PV: 4 key-chunks x 2 d-tiles ----
#pragma unroll
    for (int kc = 0; kc < 4; ++kc) {
      unsigned w0 = (kc < 2) ? WA[(kc & 1) * 4 + 0] : WB[(kc & 1) * 4 + 0];
      unsigned w1 = (kc < 2) ? WA[(kc & 1) * 4 + 1] : WB[(kc & 1) * 4 + 1];
      unsigned w2 = (kc < 2) ? WA[(kc & 1) * 4 + 2] : WB[(kc & 1) * 4 + 2];
      unsigned w3 = (kc < 2) ? WA[(kc & 1) * 4 + 3] : WB[(kc & 1) * 4 + 3];
      asm volatile("v_permlane32_swap_b32 %0, %1" : "+v"(w0), "+v"(w2));
      asm volatile("v_permlane32_swap_b32 %0, %1" : "+v"(w1), "+v"(w3));
      union { unsigned u[4]; bf16x8 v8; } pb;
      pb.u[0] = w0; pb.u[1] = w1; pb.u[2] = w2; pb.u[3] = w3;
      __builtin_amdgcn_s_setprio(1);
#pragma unroll
      for (int dt = 0; dt < 2; ++dt) {
        const int vrow = dt * 32 + ql;
        bf16x8 va = *(const bf16x8*)(VtB + ((vrow * 128 + kc * 32 + hi * 16) ^ ((ql & 7) << 4)));
        accO[dt] = __builtin_amdgcn_mfma_f32_32x32x16_bf16(va, pb.v8, accO[dt], 0, 0, 0);
      }
      __builtin_amdgcn_s_setprio(0);
    }

    asm volatile("s_waitcnt vmcnt(0)" ::: "memory");
    __builtin_amdgcn_s_barrier();
    __builtin_amdgcn_sched_barrier(0);
    cur ^= 1;
  }

  // ---- cross-wave combine; write hi/lo bf16 planes ----
  float lw = lsum + __shfl_xor(lsum, 32, 64);
  __syncthreads();
  float* cb = (float*)L + (size_t)wq * 2176 + (size_t)l * 34;
  if (wh == 1) {
#pragma unroll
    for (int dt = 0; dt < 2; ++dt)
#pragma unroll
      for (int r = 0; r < 16; ++r) cb[dt * 16 + r] = accO[dt][r];
    cb[32] = m; cb[33] = lw;
  }
  __syncthreads();
  if (wh == 0) {
    const float m1 = cb[32], l1 = cb[33];
    const float mn = fmaxf(m, m1);
    const float a0 = ex2(m - mn), a1 = ex2(m1 - mn);
    const float inv = 1.f / (lw * a0 + l1 * a1);
    const size_t rowoff = ((size_t)b * S_ + qb * 64 + wq * 32 + ql) * D_ + h * 64;
    unsigned short* xhr = xh + rowoff;
    unsigned short* xlr = xl + rowoff;
#pragma unroll
    for (int dt = 0; dt < 2; ++dt)
#pragma unroll
      for (int g0 = 0; g0 < 4; ++g0) {
        float ox = (accO[dt][4 * g0 + 0] * a0 + cb[dt * 16 + 4 * g0 + 0] * a1) * inv;
        float oy = (accO[dt][4 * g0 + 1] * a0 + cb[dt * 16 + 4 * g0 + 1] * a1) * inv;
        float oz = (accO[dt][4 * g0 + 2] * a0 + cb[dt * 16 + 4 * g0 + 2] * a1) * inv;
        float ow = (accO[dt][4 * g0 + 3] * a0 + cb[dt * 16 + 4 * g0 + 3] * a1) * inv;
        unsigned h01 = pk2(ox, oy), h23 = pk2(oz, ow);
        unsigned l01 = pk2(ox - bf16f((unsigned short)(h01 & 0xffff)),
                           oy - bf16f((unsigned short)(h01 >> 16)));
        unsigned l23 = pk2(oz - bf16f((unsigned short)(h23 & 0xffff)),
                           ow - bf16f((unsigned short)(h23 >> 16)));
        const int off = dt * 32 + hi * 4 + g0 * 8;
        uint2 uh_; uh_.x = h01; uh_.y = h23;
        uint2 ul_; ul_.x = l01; ul_.y = l23;
        *(uint2*)&xhr[off] = uh_;
        *(uint2*)&xlr[off] = ul_;
      }
  }
}

// ---------------------------------------------------------------------------
extern "C" void kernel_launch(void* const* d_in, const int* in_sizes, int n_in,
                              void* d_out, int out_size, void* d_ws, size_t ws_size,
                              hipStream_t stream) {
  const float* query = (const float*)d_in[0];
  const float* key   = (const float*)d_in[1];
  const float* value = (const float*)d_in[2];
  const float* W_fk = (const float*)d_in[4];
  const float* b_fk = (const float*)d_in[5];
  const float* W0   = (const float*)d_in[6];
  const float* b0   = (const float*)d_in[7];
  const float* Wout = (const float*)d_in[8];
  const float* bout = (const float*)d_in[9];
  float* out = (float*)d_out;

  char* ws = (char*)d_ws;
  // W^T planes (512KB each)
  unsigned short* wfk_h  = (unsigned short*)(ws);
  unsigned short* wfk_l  = (unsigned short*)(ws + (512u << 10));
  unsigned short* w0_h   = (unsigned short*)(ws + (1024u << 10));
  unsigned short* wout_h = (unsigned short*)(ws + (1536u << 10));
  unsigned short* wout_l = (unsigned short*)(ws + (2048u << 10));
  // big buffers (MB offsets); lifetimes ensure no overlap:
  float*          kfk_f32 = (float*)(ws + (3u << 20));            // 3..19, dead after pool-k
  unsigned short* q_bf16  = (unsigned short*)(ws + (3u << 20));   // 3..11 (after kfk dead)
  unsigned short* vT_bf16 = (unsigned short*)(ws + (11u << 20));  // 11..19 (after kfk dead)
  unsigned short* xh      = (unsigned short*)(ws + (19u << 20));  // 19..27
  unsigned short* xl      = (unsigned short*)(ws + (27u << 20));  // 27..35
  unsigned short* k_bf16  = (unsigned short*)(ws + (35u << 20));  // 35..43

  dim3 mgrid(D_ / 64, BS_ / 128);
  dim3 pgrid(BS_ * 64 / 256);
  const float qscale = 0.125f * 1.4426950408889634f;  // 1/sqrt(dk)*log2e

  // 0: W^T bf16 planes (one launch, all three matrices)
  wprep_kernel<<<192, 256, 0, stream>>>(W_fk, W0, Wout,
                                        wfk_h, wfk_l, w0_h, wout_h, wout_l);
  // 1: kfk = key @ W_fk + b_fk (split, f32 out)
  gemm_v3_kernel<1, 0, 0><<<mgrid, 256, 0, stream>>>(
      key, nullptr, nullptr, wfk_h, wfk_l, b_fk, kfk_f32);
  // 2: k = pool(kfk) -> bf16
  local_pool_kernel<<<pgrid, 256, 0, stream>>>(kfk_f32, k_bf16, 1.0f);
  // 3: v = value @ W0 + b0 -> V^T bf16 [b][d][s]
  gemm_v3_kernel<0, 0, 2><<<mgrid, 256, 0, stream>>>(
      value, nullptr, nullptr, w0_h, nullptr, b0, vT_bf16);
  // 4: q = pool(query) * qscale -> bf16 (overlays dead kfk region)
  local_pool_kernel<<<pgrid, 256, 0, stream>>>(query, q_bf16, qscale);
  // 5: attention -> xh/xl bf16 planes
  attn_mfma32_kernel<<<dim3(B_ * H_ * (S_ / 64)), 256, 0, stream>>>(
      q_bf16, k_bf16, vT_bf16, xh, xl);
  // 6: out = x @ Wout + bout (split, A from planes, f32 out)
  gemm_v3_kernel<1, 1, 0><<<mgrid, 256, 0, stream>>>(
      nullptr, xh, xl, wout_h, wout_l, bout, out);
}

// Round 10
// 172.101 us; speedup vs baseline: 1.2999x; 1.2999x over previous
//
#include <hip/hip_runtime.h>
#include <hip/hip_bf16.h>
#include <math.h>

#define B_  4
#define S_  2048
#define D_  512
#define H_  8
#define DK_ 64
#define BS_ (B_*S_)

using bf16x8 = __attribute__((ext_vector_type(8))) short;
using f32x4  = __attribute__((ext_vector_type(4))) float;
using f32x16 = __attribute__((ext_vector_type(16))) float;

typedef const __attribute__((address_space(1))) unsigned int gu32;
typedef __attribute__((address_space(3))) unsigned int lu32;

static __device__ inline float bf16f(unsigned short u) {
  union { unsigned u32; float f; } x; x.u32 = (unsigned)u << 16; return x.f;
}
// HW packed f32->bf16 (RNE), 1 VALU op for 2 values
static __device__ inline unsigned pk2(float a, float b) {
  unsigned r;
  asm("v_cvt_pk_bf16_f32 %0, %1, %2" : "=v"(r) : "v"(a), "v"(b));
  return r;
}
static __device__ inline float ex2(float a) {
  return __builtin_amdgcn_exp2f(a);   // raw v_exp_f32
}

// ---------------------------------------------------------------------------
// MFMA GEMM: C = A @ W + bias, bf16 split-precision (round-8 version:
// coalesced-across-lanes f32 staging + in-kernel pk2 conversion).
// OUTMODE: 0 = f32 row-major, 1 = bf16 row-major, 2 = bf16 V^T [b][n][s].
// ---------------------------------------------------------------------------
template <int SPLIT, int OUTMODE>
__global__ __launch_bounds__(256) void gemm_mfma_kernel(
    const float* __restrict__ A, const float* __restrict__ W,
    const float* __restrict__ bias, void* __restrict__ Cv) {
  const int bn = blockIdx.x;      // 8
  const int bm = blockIdx.y;      // 64
  const int tid = threadIdx.x;
  const int wv = tid >> 6, lane = tid & 63;
  const int c = lane & 15, g = lane >> 4;

  __shared__ unsigned short As[SPLIT + 1][128][72];
  __shared__ unsigned short Wt[SPLIT + 1][64][72];

  f32x4 acc[2][4];
#pragma unroll
  for (int rt = 0; rt < 2; ++rt)
#pragma unroll
    for (int ds = 0; ds < 4; ++ds) acc[rt][ds] = f32x4{0.f, 0.f, 0.f, 0.f};

  const int arow = tid >> 1, ah = (tid & 1) * 32;
  const int wn = tid & 63, wkg = (tid >> 6) * 16;

  for (int k0 = 0; k0 < D_; k0 += 64) {
    float af[32];
    const float* ag = A + ((size_t)(bm * 128 + arow)) * D_ + k0 + ah;
#pragma unroll
    for (int i = 0; i < 8; ++i) *(float4*)&af[i * 4] = *(const float4*)(ag + i * 4);
    float wf[16];
    const float* wg = W + (size_t)(k0 + wkg) * D_ + bn * 64 + wn;
#pragma unroll
    for (int i = 0; i < 16; ++i) wf[i] = wg[(size_t)i * D_];

    __syncthreads();
#pragma unroll
    for (int grp = 0; grp < 4; ++grp) {
      unsigned h[4], l[4];
#pragma unroll
      for (int p = 0; p < 4; ++p) {
        float f0 = af[grp * 8 + p * 2], f1 = af[grp * 8 + p * 2 + 1];
        h[p] = pk2(f0, f1);
        if constexpr (SPLIT)
          l[p] = pk2(f0 - bf16f((unsigned short)(h[p] & 0xffff)),
                     f1 - bf16f((unsigned short)(h[p] >> 16)));
      }
      uint4 uh; uh.x = h[0]; uh.y = h[1]; uh.z = h[2]; uh.w = h[3];
      *(uint4*)&As[0][arow][ah + grp * 8] = uh;
      if constexpr (SPLIT) {
        uint4 ul; ul.x = l[0]; ul.y = l[1]; ul.z = l[2]; ul.w = l[3];
        *(uint4*)&As[1][arow][ah + grp * 8] = ul;
      }
    }
#pragma unroll
    for (int grp = 0; grp < 2; ++grp) {
      unsigned h[4], l[4];
#pragma unroll
      for (int p = 0; p < 4; ++p) {
        float f0 = wf[grp * 8 + p * 2], f1 = wf[grp * 8 + p * 2 + 1];
        h[p] = pk2(f0, f1);
        if constexpr (SPLIT)
          l[p] = pk2(f0 - bf16f((unsigned short)(h[p] & 0xffff)),
                     f1 - bf16f((unsigned short)(h[p] >> 16)));
      }
      uint4 uh; uh.x = h[0]; uh.y = h[1]; uh.z = h[2]; uh.w = h[3];
      *(uint4*)&Wt[0][wn][wkg + grp * 8] = uh;
      if constexpr (SPLIT) {
        uint4 ul; ul.x = l[0]; ul.y = l[1]; ul.z = l[2]; ul.w = l[3];
        *(uint4*)&Wt[1][wn][wkg + grp * 8] = ul;
      }
    }
    __syncthreads();

#pragma unroll
    for (int ksub = 0; ksub < 2; ++ksub) {
      bf16x8 bh[2], bl[2];
#pragma unroll
      for (int rt = 0; rt < 2; ++rt) {
        bh[rt] = *(const bf16x8*)&As[0][wv * 32 + rt * 16 + c][ksub * 32 + g * 8];
        if constexpr (SPLIT)
          bl[rt] = *(const bf16x8*)&As[1][wv * 32 + rt * 16 + c][ksub * 32 + g * 8];
      }
#pragma unroll
      for (int ds = 0; ds < 4; ++ds) {
        bf16x8 ah_ = *(const bf16x8*)&Wt[0][ds * 16 + c][ksub * 32 + g * 8];
#pragma unroll
        for (int rt = 0; rt < 2; ++rt)
          acc[rt][ds] = __builtin_amdgcn_mfma_f32_16x16x32_bf16(ah_, bh[rt], acc[rt][ds], 0, 0, 0);
        if constexpr (SPLIT) {
          bf16x8 al_ = *(const bf16x8*)&Wt[1][ds * 16 + c][ksub * 32 + g * 8];
#pragma unroll
          for (int rt = 0; rt < 2; ++rt) {
            acc[rt][ds] = __builtin_amdgcn_mfma_f32_16x16x32_bf16(ah_, bl[rt], acc[rt][ds], 0, 0, 0);
            acc[rt][ds] = __builtin_amdgcn_mfma_f32_16x16x32_bf16(al_, bh[rt], acc[rt][ds], 0, 0, 0);
          }
        }
      }
    }
  }

#pragma unroll
  for (int rt = 0; rt < 2; ++rt) {
    const size_t m = (size_t)bm * 128 + wv * 32 + rt * 16 + c;
#pragma unroll
    for (int ds = 0; ds < 4; ++ds) {
      const int n = bn * 64 + ds * 16 + 4 * g;
      float4 bv = *(const float4*)&bias[n];
      float o0 = acc[rt][ds][0] + bv.x, o1 = acc[rt][ds][1] + bv.y;
      float o2 = acc[rt][ds][2] + bv.z, o3 = acc[rt][ds][3] + bv.w;
      if constexpr (OUTMODE == 1) {
        uint2 p; p.x = pk2(o0, o1); p.y = pk2(o2, o3);
        *(uint2*)((unsigned short*)Cv + m * D_ + n) = p;
      } else if constexpr (OUTMODE == 2) {
        // V^T: [b][n][s]; b = m>>11, s = m&2047 (block never crosses batch)
        const unsigned u01 = pk2(o0, o1), u23 = pk2(o2, o3);
        unsigned short* base =
            (unsigned short*)Cv + ((size_t)(m >> 11) * D_ + n) * (size_t)S_ + (m & 2047);
        base[0]      = (unsigned short)u01;
        base[S_]     = (unsigned short)(u01 >> 16);
        base[2 * S_] = (unsigned short)u23;
        base[3 * S_] = (unsigned short)(u23 >> 16);
      } else {
        float4 o; o.x = o0; o.y = o1; o.z = o2; o.w = o3;
        *(float4*)((float*)Cv + m * D_ + n) = o;
      }
    }
  }
}

// ---------------------------------------------------------------------------
// Causal local-window (L=5) softmax pooling; f32 in, bf16 out (scaled).
// ---------------------------------------------------------------------------
__global__ __launch_bounds__(256) void local_pool_kernel(
    const float* __restrict__ x, unsigned short* __restrict__ out,
    float oscale) {
  const int gtid = blockIdx.x * 256 + threadIdx.x;
  const int wave = gtid >> 6;
  const int lane = gtid & 63;
  if (wave >= BS_) return;
  const int b = wave / S_, s = wave % S_;
  const float* xrow = x + ((size_t)b * S_ + s) * D_;
  const int d0 = lane * 8;
  float xi[8];
  *(float4*)&xi[0] = *(const float4*)&xrow[d0];
  *(float4*)&xi[4] = *(const float4*)&xrow[d0 + 4];
  float win[5][8];
  float sc[5];
#pragma unroll
  for (int j = 0; j < 5; ++j) {
    int src = s - 4 + j;
    float part = 0.f;
    if (src >= 0) {
      const float* wr = x + ((size_t)b * S_ + src) * D_;
      *(float4*)&win[j][0] = *(const float4*)&wr[d0];
      *(float4*)&win[j][4] = *(const float4*)&wr[d0 + 4];
#pragma unroll
      for (int t = 0; t < 8; ++t) part += xi[t] * win[j][t];
    } else {
#pragma unroll
      for (int t = 0; t < 8; ++t) win[j][t] = 0.f;
    }
    sc[j] = part;
  }
#pragma unroll
  for (int off = 1; off < 64; off <<= 1) {
#pragma unroll
    for (int j = 0; j < 5; ++j) sc[j] += __shfl_xor(sc[j], off, 64);
  }
  const float scale = 0.04419417382415922f;  // 1/sqrt(512)
  float m = sc[0] * scale;
#pragma unroll
  for (int j = 1; j < 5; ++j) m = fmaxf(m, sc[j] * scale);
  float w[5], lsum = 0.f;
#pragma unroll
  for (int j = 0; j < 5; ++j) { w[j] = expf(sc[j] * scale - m); lsum += w[j]; }
  const float inv = oscale / lsum;
  float o[8] = {};
#pragma unroll
  for (int j = 0; j < 5; ++j)
#pragma unroll
    for (int t = 0; t < 8; ++t) o[t] += w[j] * win[j][t];
  unsigned short* orow = out + ((size_t)b * S_ + s) * D_;
  uint4 pk;
  pk.x = pk2(o[0] * inv, o[1] * inv);
  pk.y = pk2(o[2] * inv, o[3] * inv);
  pk.z = pk2(o[4] * inv, o[5] * inv);
  pk.w = pk2(o[6] * inv, o[7] * inv);
  *(uint4*)&orow[d0] = pk;
}

// ---------------------------------------------------------------------------
// 32x32x16 MFMA flash attention, 2-way KV-split.
// Round-8 structure EXCEPT: V is single-buffered (K stays double-buffered),
// LDS 64KB -> 48KB, so occupancy rises to 3 blocks/CU = 12 waves/CU
// (launch_bounds (256,3): 170-VGPR cap fits the ~150-reg live set, no spill).
// Counted-vmcnt protocol (never drain mid-loop):
//   tile t: QK^T(t) from K[cur]     (landed+visible via prev tail)
//           ISSUE K(t+1) -> K[cur^1]  (WAR safe: K(t-1) reads done @ t-1)
//           softmax(t)
//           vmcnt(4) [waits V(t); K(t+1) may fly; last tile: vmcnt(0)]
//           barrier  -> PV(t) from V
//           barrier  (all waves done reading V)
//           ISSUE V(t+1); vmcnt(4) [waits K(t+1)]; barrier
// Hand-checked for t=0, steady state, and t=14/15 tails.
// ---------------------------------------------------------------------------
__global__ __launch_bounds__(256, 3) void attn_mfma32_kernel(
    const unsigned short* __restrict__ q, const unsigned short* __restrict__ k,
    const unsigned short* __restrict__ vt, float* __restrict__ x) {
  const int bid = (blockIdx.x & 7) * 128 + (blockIdx.x >> 3);  // XCD swizzle
  const int qb = bid & 31;             // 64-row q-block
  const int h  = (bid >> 5) & 7;
  const int b  = bid >> 8;
  const int tid = threadIdx.x;
  const int w = tid >> 6, l = tid & 63;
  const int ql = l & 31, hi = l >> 5;
  const int wq = w & 1, wh = w >> 1;

  __shared__ __align__(16) unsigned short Kb[2][2][4096];  // [buf][half] 32KB
  __shared__ __align__(16) unsigned short Vb[2][4096];     // [half]     16KB

  bf16x8 Qf[4];
  {
    const unsigned short* qg =
        q + ((size_t)b * S_ + qb * 64 + wq * 32 + ql) * D_ + h * 64 + hi * 8;
#pragma unroll
    for (int f = 0; f < 4; ++f) Qf[f] = *(const bf16x8*)(qg + f * 16);
  }

  f32x16 accO[2] = {};           // O^T: [d-tile 32][q]
  float m = -INFINITY, lsum = 0.f;

  const int lr8 = l >> 3, lc = l & 7;
  const unsigned short* kg =
      k + ((size_t)b * S_ + wh * 1024 + wq * 32 + lr8) * D_ + h * 64 + ((lc ^ lr8) << 3);
  const unsigned short* vg =
      vt + ((size_t)b * D_ + h * 64 + wq * 32 + lr8) * (size_t)S_ + wh * 1024 + ((lc ^ lr8) << 3);

  auto ISSUE_K = [&](int t, int bf) {
    const unsigned short* kp = kg + (size_t)t * 64 * D_;
    char* dk = (char*)&Kb[bf][wh][0] + wq * 4096;
#pragma unroll
    for (int j = 0; j < 4; ++j)
      __builtin_amdgcn_global_load_lds((gu32*)(kp + (size_t)j * 8 * D_),
                                       (lu32*)(dk + j * 1024), 16, 0, 0);
  };
  auto ISSUE_V = [&](int t) {
    const unsigned short* vp = vg + t * 64;
    char* dv = (char*)&Vb[wh][0] + wq * 4096;
#pragma unroll
    for (int j = 0; j < 4; ++j)
      __builtin_amdgcn_global_load_lds((gu32*)(vp + (size_t)j * 8 * S_),
                                       (lu32*)(dv + j * 1024), 16, 0, 0);
  };

  // prologue: tile 0 K+V
  ISSUE_K(0, 0);
  ISSUE_V(0);
  asm volatile("s_waitcnt vmcnt(0)" ::: "memory");
  __builtin_amdgcn_s_barrier();
  __builtin_amdgcn_sched_barrier(0);

  int cur = 0;
  for (int kt = 0; kt < 16; ++kt) {
    const char* KsB = (const char*)&Kb[cur][wh][0];
    const char* VtB = (const char*)&Vb[wh][0];

    // ---- QK^T: two 32-key subtiles ----
    f32x16 sA = {}, sB = {};
    __builtin_amdgcn_s_setprio(1);
#pragma unroll
    for (int f = 0; f < 4; ++f) {
      bf16x8 a0 = *(const bf16x8*)(KsB + ((ql * 128 + f * 32 + hi * 16) ^ ((ql & 7) << 4)));
      bf16x8 a1 = *(const bf16x8*)(KsB + (((ql + 32) * 128 + f * 32 + hi * 16) ^ ((ql & 7) << 4)));
      sA = __builtin_amdgcn_mfma_f32_32x32x16_bf16(a0, Qf[f], sA, 0, 0, 0);
      sB = __builtin_amdgcn_mfma_f32_32x32x16_bf16(a1, Qf[f], sB, 0, 0, 0);
    }
    __builtin_amdgcn_s_setprio(0);

    if (kt + 1 < 16) ISSUE_K(kt + 1, cur ^ 1);   // lands under softmax+PV
    __builtin_amdgcn_sched_barrier(0);

    // ---- tree max, defer-max THR=10 ----
    float mx[8];
#pragma unroll
    for (int r = 0; r < 8; ++r)
      mx[r] = fmaxf(fmaxf(sA[r], sA[r + 8]), fmaxf(sB[r], sB[r + 8]));
    mx[0] = fmaxf(mx[0], mx[4]); mx[1] = fmaxf(mx[1], mx[5]);
    mx[2] = fmaxf(mx[2], mx[6]); mx[3] = fmaxf(mx[3], mx[7]);
    mx[0] = fmaxf(fmaxf(mx[0], mx[1]), fmaxf(mx[2], mx[3]));
    const float mt = fmaxf(mx[0], __shfl_xor(mx[0], 32, 64));
    if (!__all(mt <= m + 10.0f)) {
      const float mn = fmaxf(m, mt);
      const float corr = ex2(m - mn);
      m = mn;
      lsum *= corr;
#pragma unroll
      for (int dt = 0; dt < 2; ++dt)
#pragma unroll
        for (int r = 0; r < 16; ++r) accO[dt][r] *= corr;
    }

    // ---- fused exp2 -> pack -> pairwise sum ----
    unsigned WA[8], WB[8];
    float s0 = 0.f, s1 = 0.f, s2 = 0.f, s3 = 0.f;
#pragma unroll
    for (int t = 0; t < 4; ++t) {
      float a0 = ex2(sA[4 * t + 0] - m), a1 = ex2(sA[4 * t + 1] - m);
      float a2 = ex2(sA[4 * t + 2] - m), a3 = ex2(sA[4 * t + 3] - m);
      WA[2 * t] = pk2(a0, a1); WA[2 * t + 1] = pk2(a2, a3);
      s0 += a0 + a1; s1 += a2 + a3;
      float b0 = ex2(sB[4 * t + 0] - m), b1 = ex2(sB[4 * t + 1] - m);
      float b2 = ex2(sB[4 * t + 2] - m), b3 = ex2(sB[4 * t + 3] - m);
      WB[2 * t] = pk2(b0, b1); WB[2 * t + 1] = pk2(b2, b3);
      s2 += b0 + b1; s3 += b2 + b3;
    }
    lsum += (s0 + s1) + (s2 + s3);

    // ---- wait V(t) (counted: K(t+1) may stay in flight), make visible ----
    if (kt + 1 < 16) asm volatile("s_waitcnt vmcnt(4)" ::: "memory");
    else             asm volatile("s_waitcnt vmcnt(0)" ::: "memory");
    __builtin_amdgcn_s_barrier();
    __builtin_amdgcn_sched_barrier(0);

    // ---- PV: 4 key-chunks x 2 d-tiles ----
#pragma unroll
    for (int kc = 0; kc < 4; ++kc) {
      unsigned w0 = (kc < 2) ? WA[(kc & 1) * 4 + 0] : WB[(kc & 1) * 4 + 0];
      unsigned w1 = (kc < 2) ? WA[(kc & 1) * 4 + 1] : WB[(kc & 1) * 4 + 1];
      unsigned w2 = (kc < 2) ? WA[(kc & 1) * 4 + 2] : WB[(kc & 1) * 4 + 2];
      unsigned w3 = (kc < 2) ? WA[(kc & 1) * 4 + 3] : WB[(kc & 1) * 4 + 3];
      asm volatile("v_permlane32_swap_b32 %0, %1" : "+v"(w0), "+v"(w2));
      asm volatile("v_permlane32_swap_b32 %0, %1" : "+v"(w1), "+v"(w3));
      union { unsigned u[4]; bf16x8 v8; } pb;
      pb.u[0] = w0; pb.u[1] = w1; pb.u[2] = w2; pb.u[3] = w3;
      __builtin_amdgcn_s_setprio(1);
#pragma unroll
      for (int dt = 0; dt < 2; ++dt) {
        const int vrow = dt * 32 + ql;
        bf16x8 va = *(const bf16x8*)(VtB + ((vrow * 128 + kc * 32 + hi * 16) ^ ((ql & 7) << 4)));
        accO[dt] = __builtin_amdgcn_mfma_f32_32x32x16_bf16(va, pb.v8, accO[dt], 0, 0, 0);
      }
      __builtin_amdgcn_s_setprio(0);
    }

    // ---- V buffer recycle: all waves done reading, then refill ----
    __builtin_amdgcn_s_barrier();
    __builtin_amdgcn_sched_barrier(0);
    if (kt + 1 < 16) {
      ISSUE_V(kt + 1);
      asm volatile("s_waitcnt vmcnt(4)" ::: "memory");  // waits K(t+1); V(t+1) flies
      __builtin_amdgcn_s_barrier();
      __builtin_amdgcn_sched_barrier(0);
    }
    cur ^= 1;
  }

  // ---- cross-wave combine (halves share q-subtile); reuse Kb as scratch ----
  float lw = lsum + __shfl_xor(lsum, 32, 64);
  __syncthreads();                        // all waves done with tiles
  float* cb = (float*)Kb + (size_t)wq * 2176 + (size_t)l * 34;
  if (wh == 1) {
#pragma unroll
    for (int dt = 0; dt < 2; ++dt)
#pragma unroll
      for (int r = 0; r < 16; ++r) cb[dt * 16 + r] = accO[dt][r];
    cb[32] = m; cb[33] = lw;
  }
  __syncthreads();
  if (wh == 0) {
    const float m1 = cb[32], l1 = cb[33];
    const float mn = fmaxf(m, m1);
    const float a0 = ex2(m - mn), a1 = ex2(m1 - mn);
    const float inv = 1.f / (lw * a0 + l1 * a1);
    float* xrow = x + ((size_t)b * S_ + qb * 64 + wq * 32 + ql) * D_ + h * 64;
#pragma unroll
    for (int dt = 0; dt < 2; ++dt)
#pragma unroll
      for (int g0 = 0; g0 < 4; ++g0) {
        float4 o;
        o.x = (accO[dt][4 * g0 + 0] * a0 + cb[dt * 16 + 4 * g0 + 0] * a1) * inv;
        o.y = (accO[dt][4 * g0 + 1] * a0 + cb[dt * 16 + 4 * g0 + 1] * a1) * inv;
        o.z = (accO[dt][4 * g0 + 2] * a0 + cb[dt * 16 + 4 * g0 + 2] * a1) * inv;
        o.w = (accO[dt][4 * g0 + 3] * a0 + cb[dt * 16 + 4 * g0 + 3] * a1) * inv;
        *(float4*)&xrow[dt * 32 + hi * 4 + g0 * 8] = o;
      }
  }
}

// ---------------------------------------------------------------------------
extern "C" void kernel_launch(void* const* d_in, const int* in_sizes, int n_in,
                              void* d_out, int out_size, void* d_ws, size_t ws_size,
                              hipStream_t stream) {
  const float* query = (const float*)d_in[0];
  const float* key   = (const float*)d_in[1];
  const float* value = (const float*)d_in[2];
  const float* W_fk = (const float*)d_in[4];
  const float* b_fk = (const float*)d_in[5];
  const float* W0   = (const float*)d_in[6];
  const float* b0   = (const float*)d_in[7];
  const float* Wout = (const float*)d_in[8];
  const float* bout = (const float*)d_in[9];
  float* out = (float*)d_out;

  char* ws = (char*)d_ws;
  float* kfk_f32   = (float*)ws;                       // 16MB @ 0 (later q_bf16)
  float* x_f32     = (float*)(ws + (16u << 20));       // 16MB @ 16MB
  unsigned short* k_bf16 = (unsigned short*)(ws + (32u << 20));  // 8MB @ 32MB
  unsigned short* vT_bf16 = (unsigned short*)(ws + (40u << 20)); // 8MB @ 40MB, [b][d][s]
  unsigned short* q_bf16 = (unsigned short*)ws;        // overlays kfk after use

  dim3 mgrid(D_ / 64, BS_ / 128);
  dim3 pgrid(BS_ * 64 / 256);
  // 1/sqrt(dk) * log2(e): softmax runs in exp2 domain
  const float qscale = 0.125f * 1.4426950408889634f;

  gemm_mfma_kernel<1, 0><<<mgrid, 256, 0, stream>>>(key, W_fk, b_fk, kfk_f32);
  local_pool_kernel<<<pgrid, 256, 0, stream>>>(kfk_f32, k_bf16, 1.0f);
  gemm_mfma_kernel<0, 2><<<mgrid, 256, 0, stream>>>(value, W0, b0, vT_bf16);
  local_pool_kernel<<<pgrid, 256, 0, stream>>>(query, q_bf16, qscale);
  attn_mfma32_kernel<<<dim3(B_ * H_ * (S_ / 64)), 256, 0, stream>>>(q_bf16, k_bf16, vT_bf16, x_f32);
  gemm_mfma_kernel<1, 0><<<mgrid, 256, 0, stream>>>(x_f32, Wout, bout, out);
}

// Round 11
// 163.944 us; speedup vs baseline: 1.3646x; 1.0498x over previous
//
#include <hip/hip_runtime.h>
#include <hip/hip_bf16.h>
#include <math.h>

#define B_  4
#define S_  2048
#define D_  512
#define H_  8
#define DK_ 64
#define BS_ (B_*S_)

using bf16x8 = __attribute__((ext_vector_type(8))) short;
using f32x4  = __attribute__((ext_vector_type(4))) float;
using f32x16 = __attribute__((ext_vector_type(16))) float;

typedef const __attribute__((address_space(1))) unsigned int gu32;
typedef __attribute__((address_space(3))) unsigned int lu32;

static __device__ inline float bf16f(unsigned short u) {
  union { unsigned u32; float f; } x; x.u32 = (unsigned)u << 16; return x.f;
}
// HW packed f32->bf16 (RNE), 1 VALU op for 2 values
static __device__ inline unsigned pk2(float a, float b) {
  unsigned r;
  asm("v_cvt_pk_bf16_f32 %0, %1, %2" : "=v"(r) : "v"(a), "v"(b));
  return r;
}
static __device__ inline float ex2(float a) {
  return __builtin_amdgcn_exp2f(a);   // raw v_exp_f32
}

// ---------------------------------------------------------------------------
// GEMM body (device-inline): C[128x64 tile] = A @ W + bias, bf16
// split-precision, identical math to round-10 gemm_mfma_kernel. LDS is a
// caller-provided arena so independent GEMMs can share one kernel.
// OUTMODE: 0 = f32 row-major, 2 = bf16 V^T [b][n][s].
// ---------------------------------------------------------------------------
template <int SPLIT, int OUTMODE>
static __device__ __forceinline__ void gemm_body(
    const float* __restrict__ A, const float* __restrict__ W,
    const float* __restrict__ bias, void* __restrict__ Cv,
    int bn, int bm, char* lds) {
  unsigned short (*As)[128][72] = (unsigned short(*)[128][72])lds;
  unsigned short (*Wt)[64][72] =
      (unsigned short(*)[64][72])(lds + (size_t)(SPLIT + 1) * 128 * 72 * 2);
  const int tid = threadIdx.x;
  const int wv = tid >> 6, lane = tid & 63;
  const int c = lane & 15, g = lane >> 4;

  f32x4 acc[2][4];
#pragma unroll
  for (int rt = 0; rt < 2; ++rt)
#pragma unroll
    for (int ds = 0; ds < 4; ++ds) acc[rt][ds] = f32x4{0.f, 0.f, 0.f, 0.f};

  const int arow = tid >> 1, ah = (tid & 1) * 32;
  const int wn = tid & 63, wkg = (tid >> 6) * 16;

  for (int k0 = 0; k0 < D_; k0 += 64) {
    float af[32];
    const float* ag = A + ((size_t)(bm * 128 + arow)) * D_ + k0 + ah;
#pragma unroll
    for (int i = 0; i < 8; ++i) *(float4*)&af[i * 4] = *(const float4*)(ag + i * 4);
    float wf[16];
    const float* wg = W + (size_t)(k0 + wkg) * D_ + bn * 64 + wn;
#pragma unroll
    for (int i = 0; i < 16; ++i) wf[i] = wg[(size_t)i * D_];

    __syncthreads();
#pragma unroll
    for (int grp = 0; grp < 4; ++grp) {
      unsigned h[4], l[4];
#pragma unroll
      for (int p = 0; p < 4; ++p) {
        float f0 = af[grp * 8 + p * 2], f1 = af[grp * 8 + p * 2 + 1];
        h[p] = pk2(f0, f1);
        if constexpr (SPLIT)
          l[p] = pk2(f0 - bf16f((unsigned short)(h[p] & 0xffff)),
                     f1 - bf16f((unsigned short)(h[p] >> 16)));
      }
      uint4 uh; uh.x = h[0]; uh.y = h[1]; uh.z = h[2]; uh.w = h[3];
      *(uint4*)&As[0][arow][ah + grp * 8] = uh;
      if constexpr (SPLIT) {
        uint4 ul; ul.x = l[0]; ul.y = l[1]; ul.z = l[2]; ul.w = l[3];
        *(uint4*)&As[1][arow][ah + grp * 8] = ul;
      }
    }
#pragma unroll
    for (int grp = 0; grp < 2; ++grp) {
      unsigned h[4], l[4];
#pragma unroll
      for (int p = 0; p < 4; ++p) {
        float f0 = wf[grp * 8 + p * 2], f1 = wf[grp * 8 + p * 2 + 1];
        h[p] = pk2(f0, f1);
        if constexpr (SPLIT)
          l[p] = pk2(f0 - bf16f((unsigned short)(h[p] & 0xffff)),
                     f1 - bf16f((unsigned short)(h[p] >> 16)));
      }
      uint4 uh; uh.x = h[0]; uh.y = h[1]; uh.z = h[2]; uh.w = h[3];
      *(uint4*)&Wt[0][wn][wkg + grp * 8] = uh;
      if constexpr (SPLIT) {
        uint4 ul; ul.x = l[0]; ul.y = l[1]; ul.z = l[2]; ul.w = l[3];
        *(uint4*)&Wt[1][wn][wkg + grp * 8] = ul;
      }
    }
    __syncthreads();

#pragma unroll
    for (int ksub = 0; ksub < 2; ++ksub) {
      bf16x8 bh[2], bl[2];
#pragma unroll
      for (int rt = 0; rt < 2; ++rt) {
        bh[rt] = *(const bf16x8*)&As[0][wv * 32 + rt * 16 + c][ksub * 32 + g * 8];
        if constexpr (SPLIT)
          bl[rt] = *(const bf16x8*)&As[1][wv * 32 + rt * 16 + c][ksub * 32 + g * 8];
      }
#pragma unroll
      for (int ds = 0; ds < 4; ++ds) {
        bf16x8 ah_ = *(const bf16x8*)&Wt[0][ds * 16 + c][ksub * 32 + g * 8];
#pragma unroll
        for (int rt = 0; rt < 2; ++rt)
          acc[rt][ds] = __builtin_amdgcn_mfma_f32_16x16x32_bf16(ah_, bh[rt], acc[rt][ds], 0, 0, 0);
        if constexpr (SPLIT) {
          bf16x8 al_ = *(const bf16x8*)&Wt[1][ds * 16 + c][ksub * 32 + g * 8];
#pragma unroll
          for (int rt = 0; rt < 2; ++rt) {
            acc[rt][ds] = __builtin_amdgcn_mfma_f32_16x16x32_bf16(ah_, bl[rt], acc[rt][ds], 0, 0, 0);
            acc[rt][ds] = __builtin_amdgcn_mfma_f32_16x16x32_bf16(al_, bh[rt], acc[rt][ds], 0, 0, 0);
          }
        }
      }
    }
  }

#pragma unroll
  for (int rt = 0; rt < 2; ++rt) {
    const size_t m = (size_t)bm * 128 + wv * 32 + rt * 16 + c;
#pragma unroll
    for (int ds = 0; ds < 4; ++ds) {
      const int n = bn * 64 + ds * 16 + 4 * g;
      float4 bv = *(const float4*)&bias[n];
      float o0 = acc[rt][ds][0] + bv.x, o1 = acc[rt][ds][1] + bv.y;
      float o2 = acc[rt][ds][2] + bv.z, o3 = acc[rt][ds][3] + bv.w;
      if constexpr (OUTMODE == 2) {
        // V^T: [b][n][s]; b = m>>11, s = m&2047 (block never crosses batch)
        const unsigned u01 = pk2(o0, o1), u23 = pk2(o2, o3);
        unsigned short* base =
            (unsigned short*)Cv + ((size_t)(m >> 11) * D_ + n) * (size_t)S_ + (m & 2047);
        base[0]      = (unsigned short)u01;
        base[S_]     = (unsigned short)(u01 >> 16);
        base[2 * S_] = (unsigned short)u23;
        base[3 * S_] = (unsigned short)(u23 >> 16);
      } else {
        float4 o; o.x = o0; o.y = o1; o.z = o2; o.w = o3;
        *(float4*)((float*)Cv + m * D_ + n) = o;
      }
    }
  }
}

// Phase A: kfk split-GEMM (blocks 0..511) + v GEMM->V^T (blocks 512..1023).
__global__ __launch_bounds__(256) void gemm_pair_kernel(
    const float* __restrict__ key, const float* __restrict__ W_fk,
    const float* __restrict__ b_fk, float* __restrict__ kfk,
    const float* __restrict__ value, const float* __restrict__ W0,
    const float* __restrict__ b0, void* __restrict__ vT) {
  __shared__ __align__(16) char Lraw[55296];
  int bid = blockIdx.x;
  if (bid < 512) {
    gemm_body<1, 0>(key, W_fk, b_fk, kfk, bid & 7, bid >> 3, Lraw);
  } else {
    bid -= 512;
    gemm_body<0, 2>(value, W0, b0, vT, bid & 7, bid >> 3, Lraw);
  }
}

// Final: out = x @ Wout + bout (split).
__global__ __launch_bounds__(256) void gemm_out_kernel(
    const float* __restrict__ x, const float* __restrict__ Wout,
    const float* __restrict__ bout, float* __restrict__ out) {
  __shared__ __align__(16) char Lraw[55296];
  gemm_body<1, 0>(x, Wout, bout, out, blockIdx.x & 7, blockIdx.x >> 3, Lraw);
}

// ---------------------------------------------------------------------------
// Causal local-window (L=5) softmax pooling body; f32 in, bf16 out (scaled).
// ---------------------------------------------------------------------------
static __device__ __forceinline__ void pool_body(
    const float* __restrict__ x, unsigned short* __restrict__ out,
    float oscale, int bid) {
  const int gtid = bid * 256 + threadIdx.x;
  const int wave = gtid >> 6;
  const int lane = gtid & 63;
  const int b = wave / S_, s = wave % S_;
  const float* xrow = x + ((size_t)b * S_ + s) * D_;
  const int d0 = lane * 8;
  float xi[8];
  *(float4*)&xi[0] = *(const float4*)&xrow[d0];
  *(float4*)&xi[4] = *(const float4*)&xrow[d0 + 4];
  float win[5][8];
  float sc[5];
#pragma unroll
  for (int j = 0; j < 5; ++j) {
    int src = s - 4 + j;
    float part = 0.f;
    if (src >= 0) {
      const float* wr = x + ((size_t)b * S_ + src) * D_;
      *(float4*)&win[j][0] = *(const float4*)&wr[d0];
      *(float4*)&win[j][4] = *(const float4*)&wr[d0 + 4];
#pragma unroll
      for (int t = 0; t < 8; ++t) part += xi[t] * win[j][t];
    } else {
#pragma unroll
      for (int t = 0; t < 8; ++t) win[j][t] = 0.f;
    }
    sc[j] = part;
  }
#pragma unroll
  for (int off = 1; off < 64; off <<= 1) {
#pragma unroll
    for (int j = 0; j < 5; ++j) sc[j] += __shfl_xor(sc[j], off, 64);
  }
  const float scale = 0.04419417382415922f;  // 1/sqrt(512)
  float m = sc[0] * scale;
#pragma unroll
  for (int j = 1; j < 5; ++j) m = fmaxf(m, sc[j] * scale);
  float w[5], lsum = 0.f;
#pragma unroll
  for (int j = 0; j < 5; ++j) { w[j] = expf(sc[j] * scale - m); lsum += w[j]; }
  const float inv = oscale / lsum;
  float o[8] = {};
#pragma unroll
  for (int j = 0; j < 5; ++j)
#pragma unroll
    for (int t = 0; t < 8; ++t) o[t] += w[j] * win[j][t];
  unsigned short* orow = out + ((size_t)b * S_ + s) * D_;
  uint4 pk;
  pk.x = pk2(o[0] * inv, o[1] * inv);
  pk.y = pk2(o[2] * inv, o[3] * inv);
  pk.z = pk2(o[4] * inv, o[5] * inv);
  pk.w = pk2(o[6] * inv, o[7] * inv);
  *(uint4*)&orow[d0] = pk;
}

// Phase B: pool-k (blocks 0..2047) + pool-q (blocks 2048..4095).
__global__ __launch_bounds__(256) void pool_pair_kernel(
    const float* __restrict__ kfk, unsigned short* __restrict__ kout,
    const float* __restrict__ query, unsigned short* __restrict__ qout,
    float qscale) {
  const int bid = blockIdx.x;
  if (bid < 2048) pool_body(kfk, kout, 1.0f, bid);
  else            pool_body(query, qout, qscale, bid - 2048);
}

// ---------------------------------------------------------------------------
// 32x32x16 MFMA flash attention, 2-way KV-split (unchanged from round 10).
// ---------------------------------------------------------------------------
__global__ __launch_bounds__(256, 3) void attn_mfma32_kernel(
    const unsigned short* __restrict__ q, const unsigned short* __restrict__ k,
    const unsigned short* __restrict__ vt, float* __restrict__ x) {
  const int bid = (blockIdx.x & 7) * 128 + (blockIdx.x >> 3);  // XCD swizzle
  const int qb = bid & 31;             // 64-row q-block
  const int h  = (bid >> 5) & 7;
  const int b  = bid >> 8;
  const int tid = threadIdx.x;
  const int w = tid >> 6, l = tid & 63;
  const int ql = l & 31, hi = l >> 5;
  const int wq = w & 1, wh = w >> 1;

  __shared__ __align__(16) unsigned short Kb[2][2][4096];  // [buf][half] 32KB
  __shared__ __align__(16) unsigned short Vb[2][4096];     // [half]     16KB

  bf16x8 Qf[4];
  {
    const unsigned short* qg =
        q + ((size_t)b * S_ + qb * 64 + wq * 32 + ql) * D_ + h * 64 + hi * 8;
#pragma unroll
    for (int f = 0; f < 4; ++f) Qf[f] = *(const bf16x8*)(qg + f * 16);
  }

  f32x16 accO[2] = {};           // O^T: [d-tile 32][q]
  float m = -INFINITY, lsum = 0.f;

  const int lr8 = l >> 3, lc = l & 7;
  const unsigned short* kg =
      k + ((size_t)b * S_ + wh * 1024 + wq * 32 + lr8) * D_ + h * 64 + ((lc ^ lr8) << 3);
  const unsigned short* vg =
      vt + ((size_t)b * D_ + h * 64 + wq * 32 + lr8) * (size_t)S_ + wh * 1024 + ((lc ^ lr8) << 3);

  auto ISSUE_K = [&](int t, int bf) {
    const unsigned short* kp = kg + (size_t)t * 64 * D_;
    char* dk = (char*)&Kb[bf][wh][0] + wq * 4096;
#pragma unroll
    for (int j = 0; j < 4; ++j)
      __builtin_amdgcn_global_load_lds((gu32*)(kp + (size_t)j * 8 * D_),
                                       (lu32*)(dk + j * 1024), 16, 0, 0);
  };
  auto ISSUE_V = [&](int t) {
    const unsigned short* vp = vg + t * 64;
    char* dv = (char*)&Vb[wh][0] + wq * 4096;
#pragma unroll
    for (int j = 0; j < 4; ++j)
      __builtin_amdgcn_global_load_lds((gu32*)(vp + (size_t)j * 8 * S_),
                                       (lu32*)(dv + j * 1024), 16, 0, 0);
  };

  // prologue: tile 0 K+V
  ISSUE_K(0, 0);
  ISSUE_V(0);
  asm volatile("s_waitcnt vmcnt(0)" ::: "memory");
  __builtin_amdgcn_s_barrier();
  __builtin_amdgcn_sched_barrier(0);

  int cur = 0;
  for (int kt = 0; kt < 16; ++kt) {
    const char* KsB = (const char*)&Kb[cur][wh][0];
    const char* VtB = (const char*)&Vb[wh][0];

    // ---- QK^T: two 32-key subtiles ----
    f32x16 sA = {}, sB = {};
    __builtin_amdgcn_s_setprio(1);
#pragma unroll
    for (int f = 0; f < 4; ++f) {
      bf16x8 a0 = *(const bf16x8*)(KsB + ((ql * 128 + f * 32 + hi * 16) ^ ((ql & 7) << 4)));
      bf16x8 a1 = *(const bf16x8*)(KsB + (((ql + 32) * 128 + f * 32 + hi * 16) ^ ((ql & 7) << 4)));
      sA = __builtin_amdgcn_mfma_f32_32x32x16_bf16(a0, Qf[f], sA, 0, 0, 0);
      sB = __builtin_amdgcn_mfma_f32_32x32x16_bf16(a1, Qf[f], sB, 0, 0, 0);
    }
    __builtin_amdgcn_s_setprio(0);

    if (kt + 1 < 16) ISSUE_K(kt + 1, cur ^ 1);   // lands under softmax+PV
    __builtin_amdgcn_sched_barrier(0);

    // ---- tree max, defer-max THR=10 ----
    float mx[8];
#pragma unroll
    for (int r = 0; r < 8; ++r)
      mx[r] = fmaxf(fmaxf(sA[r], sA[r + 8]), fmaxf(sB[r], sB[r + 8]));
    mx[0] = fmaxf(mx[0], mx[4]); mx[1] = fmaxf(mx[1], mx[5]);
    mx[2] = fmaxf(mx[2], mx[6]); mx[3] = fmaxf(mx[3], mx[7]);
    mx[0] = fmaxf(fmaxf(mx[0], mx[1]), fmaxf(mx[2], mx[3]));
    const float mt = fmaxf(mx[0], __shfl_xor(mx[0], 32, 64));
    if (!__all(mt <= m + 10.0f)) {
      const float mn = fmaxf(m, mt);
      const float corr = ex2(m - mn);
      m = mn;
      lsum *= corr;
#pragma unroll
      for (int dt = 0; dt < 2; ++dt)
#pragma unroll
        for (int r = 0; r < 16; ++r) accO[dt][r] *= corr;
    }

    // ---- fused exp2 -> pack -> pairwise sum ----
    unsigned WA[8], WB[8];
    float s0 = 0.f, s1 = 0.f, s2 = 0.f, s3 = 0.f;
#pragma unroll
    for (int t = 0; t < 4; ++t) {
      float a0 = ex2(sA[4 * t + 0] - m), a1 = ex2(sA[4 * t + 1] - m);
      float a2 = ex2(sA[4 * t + 2] - m), a3 = ex2(sA[4 * t + 3] - m);
      WA[2 * t] = pk2(a0, a1); WA[2 * t + 1] = pk2(a2, a3);
      s0 += a0 + a1; s1 += a2 + a3;
      float b0 = ex2(sB[4 * t + 0] - m), b1 = ex2(sB[4 * t + 1] - m);
      float b2 = ex2(sB[4 * t + 2] - m), b3 = ex2(sB[4 * t + 3] - m);
      WB[2 * t] = pk2(b0, b1); WB[2 * t + 1] = pk2(b2, b3);
      s2 += b0 + b1; s3 += b2 + b3;
    }
    lsum += (s0 + s1) + (s2 + s3);

    // ---- wait V(t) (counted: K(t+1) may stay in flight), make visible ----
    if (kt + 1 < 16) asm volatile("s_waitcnt vmcnt(4)" ::: "memory");
    else             asm volatile("s_waitcnt vmcnt(0)" ::: "memory");
    __builtin_amdgcn_s_barrier();
    __builtin_amdgcn_sched_barrier(0);

    // ---- PV: 4 key-chunks x 2 d-tiles ----
#pragma unroll
    for (int kc = 0; kc < 4; ++kc) {
      unsigned w0 = (kc < 2) ? WA[(kc & 1) * 4 + 0] : WB[(kc & 1) * 4 + 0];
      unsigned w1 = (kc < 2) ? WA[(kc & 1) * 4 + 1] : WB[(kc & 1) * 4 + 1];
      unsigned w2 = (kc < 2) ? WA[(kc & 1) * 4 + 2] : WB[(kc & 1) * 4 + 2];
      unsigned w3 = (kc < 2) ? WA[(kc & 1) * 4 + 3] : WB[(kc & 1) * 4 + 3];
      asm volatile("v_permlane32_swap_b32 %0, %1" : "+v"(w0), "+v"(w2));
      asm volatile("v_permlane32_swap_b32 %0, %1" : "+v"(w1), "+v"(w3));
      union { unsigned u[4]; bf16x8 v8; } pb;
      pb.u[0] = w0; pb.u[1] = w1; pb.u[2] = w2; pb.u[3] = w3;
      __builtin_amdgcn_s_setprio(1);
#pragma unroll
      for (int dt = 0; dt < 2; ++dt) {
        const int vrow = dt * 32 + ql;
        bf16x8 va = *(const bf16x8*)(VtB + ((vrow * 128 + kc * 32 + hi * 16) ^ ((ql & 7) << 4)));
        accO[dt] = __builtin_amdgcn_mfma_f32_32x32x16_bf16(va, pb.v8, accO[dt], 0, 0, 0);
      }
      __builtin_amdgcn_s_setprio(0);
    }

    // ---- V buffer recycle: all waves done reading, then refill ----
    __builtin_amdgcn_s_barrier();
    __builtin_amdgcn_sched_barrier(0);
    if (kt + 1 < 16) {
      ISSUE_V(kt + 1);
      asm volatile("s_waitcnt vmcnt(4)" ::: "memory");  // waits K(t+1); V(t+1) flies
      __builtin_amdgcn_s_barrier();
      __builtin_amdgcn_sched_barrier(0);
    }
    cur ^= 1;
  }

  // ---- cross-wave combine (halves share q-subtile); reuse Kb as scratch ----
  float lw = lsum + __shfl_xor(lsum, 32, 64);
  __syncthreads();                        // all waves done with tiles
  float* cb = (float*)Kb + (size_t)wq * 2176 + (size_t)l * 34;
  if (wh == 1) {
#pragma unroll
    for (int dt = 0; dt < 2; ++dt)
#pragma unroll
      for (int r = 0; r < 16; ++r) cb[dt * 16 + r] = accO[dt][r];
    cb[32] = m; cb[33] = lw;
  }
  __syncthreads();
  if (wh == 0) {
    const float m1 = cb[32], l1 = cb[33];
    const float mn = fmaxf(m, m1);
    const float a0 = ex2(m - mn), a1 = ex2(m1 - mn);
    const float inv = 1.f / (lw * a0 + l1 * a1);
    float* xrow = x + ((size_t)b * S_ + qb * 64 + wq * 32 + ql) * D_ + h * 64;
#pragma unroll
    for (int dt = 0; dt < 2; ++dt)
#pragma unroll
      for (int g0 = 0; g0 < 4; ++g0) {
        float4 o;
        o.x = (accO[dt][4 * g0 + 0] * a0 + cb[dt * 16 + 4 * g0 + 0] * a1) * inv;
        o.y = (accO[dt][4 * g0 + 1] * a0 + cb[dt * 16 + 4 * g0 + 1] * a1) * inv;
        o.z = (accO[dt][4 * g0 + 2] * a0 + cb[dt * 16 + 4 * g0 + 2] * a1) * inv;
        o.w = (accO[dt][4 * g0 + 3] * a0 + cb[dt * 16 + 4 * g0 + 3] * a1) * inv;
        *(float4*)&xrow[dt * 32 + hi * 4 + g0 * 8] = o;
      }
  }
}

// ---------------------------------------------------------------------------
extern "C" void kernel_launch(void* const* d_in, const int* in_sizes, int n_in,
                              void* d_out, int out_size, void* d_ws, size_t ws_size,
                              hipStream_t stream) {
  const float* query = (const float*)d_in[0];
  const float* key   = (const float*)d_in[1];
  const float* value = (const float*)d_in[2];
  const float* W_fk = (const float*)d_in[4];
  const float* b_fk = (const float*)d_in[5];
  const float* W0   = (const float*)d_in[6];
  const float* b0   = (const float*)d_in[7];
  const float* Wout = (const float*)d_in[8];
  const float* bout = (const float*)d_in[9];
  float* out = (float*)d_out;

  char* ws = (char*)d_ws;
  float* kfk_f32   = (float*)ws;                       // 16MB @ 0 (later q_bf16)
  float* x_f32     = (float*)(ws + (16u << 20));       // 16MB @ 16MB
  unsigned short* k_bf16 = (unsigned short*)(ws + (32u << 20));  // 8MB @ 32MB
  unsigned short* vT_bf16 = (unsigned short*)(ws + (40u << 20)); // 8MB @ 40MB, [b][d][s]
  unsigned short* q_bf16 = (unsigned short*)(ws + (48u << 20));  // 8MB @ 48MB

  // 1/sqrt(dk) * log2(e): softmax runs in exp2 domain
  const float qscale = 0.125f * 1.4426950408889634f;

  // A: kfk = key@W_fk+b_fk (f32)  ||  vT = (value@W0+b0)^T (bf16)
  gemm_pair_kernel<<<1024, 256, 0, stream>>>(key, W_fk, b_fk, kfk_f32,
                                             value, W0, b0, vT_bf16);
  // B: k = pool(kfk) -> bf16  ||  q = pool(query)*qscale -> bf16
  pool_pair_kernel<<<4096, 256, 0, stream>>>(kfk_f32, k_bf16, query, q_bf16, qscale);
  // C: attention -> f32
  attn_mfma32_kernel<<<dim3(B_ * H_ * (S_ / 64)), 256, 0, stream>>>(
      q_bf16, k_bf16, vT_bf16, x_f32);
  // D: out = x @ Wout + bout
  gemm_out_kernel<<<512, 256, 0, stream>>>(x_f32, Wout, bout, out);
}

// Round 12
// 156.361 us; speedup vs baseline: 1.4307x; 1.0485x over previous
//
#include <hip/hip_runtime.h>
#include <hip/hip_bf16.h>
#include <math.h>

#define B_  4
#define S_  2048
#define D_  512
#define H_  8
#define DK_ 64
#define BS_ (B_*S_)

using bf16x8 = __attribute__((ext_vector_type(8))) short;
using f32x4  = __attribute__((ext_vector_type(4))) float;
using f32x16 = __attribute__((ext_vector_type(16))) float;

typedef const __attribute__((address_space(1))) unsigned int gu32;
typedef __attribute__((address_space(3))) unsigned int lu32;

static __device__ inline float bf16f(unsigned short u) {
  union { unsigned u32; float f; } x; x.u32 = (unsigned)u << 16; return x.f;
}
// HW packed f32->bf16 (RNE), 1 VALU op for 2 values
static __device__ inline unsigned pk2(float a, float b) {
  unsigned r;
  asm("v_cvt_pk_bf16_f32 %0, %1, %2" : "=v"(r) : "v"(a), "v"(b));
  return r;
}
static __device__ inline float ex2(float a) {
  return __builtin_amdgcn_exp2f(a);   // raw v_exp_f32
}

// ---------------------------------------------------------------------------
// GEMM body (device-inline): C[128x64 tile] = A @ W + bias, bf16
// (split-precision when SPLIT=1). LDS arena provided by caller.
// OUTMODE: 0 = f32 row-major, 1 = bf16 row-major, 2 = bf16 V^T [b][n][s].
// ---------------------------------------------------------------------------
template <int SPLIT, int OUTMODE>
static __device__ __forceinline__ void gemm_body(
    const float* __restrict__ A, const float* __restrict__ W,
    const float* __restrict__ bias, void* __restrict__ Cv,
    int bn, int bm, char* lds) {
  unsigned short (*As)[128][72] = (unsigned short(*)[128][72])lds;
  unsigned short (*Wt)[64][72] =
      (unsigned short(*)[64][72])(lds + (size_t)(SPLIT + 1) * 128 * 72 * 2);
  const int tid = threadIdx.x;
  const int wv = tid >> 6, lane = tid & 63;
  const int c = lane & 15, g = lane >> 4;

  f32x4 acc[2][4];
#pragma unroll
  for (int rt = 0; rt < 2; ++rt)
#pragma unroll
    for (int ds = 0; ds < 4; ++ds) acc[rt][ds] = f32x4{0.f, 0.f, 0.f, 0.f};

  const int arow = tid >> 1, ah = (tid & 1) * 32;
  const int wn = tid & 63, wkg = (tid >> 6) * 16;

  for (int k0 = 0; k0 < D_; k0 += 64) {
    float af[32];
    const float* ag = A + ((size_t)(bm * 128 + arow)) * D_ + k0 + ah;
#pragma unroll
    for (int i = 0; i < 8; ++i) *(float4*)&af[i * 4] = *(const float4*)(ag + i * 4);
    float wf[16];
    const float* wg = W + (size_t)(k0 + wkg) * D_ + bn * 64 + wn;
#pragma unroll
    for (int i = 0; i < 16; ++i) wf[i] = wg[(size_t)i * D_];

    __syncthreads();
#pragma unroll
    for (int grp = 0; grp < 4; ++grp) {
      unsigned h[4], l[4];
#pragma unroll
      for (int p = 0; p < 4; ++p) {
        float f0 = af[grp * 8 + p * 2], f1 = af[grp * 8 + p * 2 + 1];
        h[p] = pk2(f0, f1);
        if constexpr (SPLIT)
          l[p] = pk2(f0 - bf16f((unsigned short)(h[p] & 0xffff)),
                     f1 - bf16f((unsigned short)(h[p] >> 16)));
      }
      uint4 uh; uh.x = h[0]; uh.y = h[1]; uh.z = h[2]; uh.w = h[3];
      *(uint4*)&As[0][arow][ah + grp * 8] = uh;
      if constexpr (SPLIT) {
        uint4 ul; ul.x = l[0]; ul.y = l[1]; ul.z = l[2]; ul.w = l[3];
        *(uint4*)&As[1][arow][ah + grp * 8] = ul;
      }
    }
#pragma unroll
    for (int grp = 0; grp < 2; ++grp) {
      unsigned h[4], l[4];
#pragma unroll
      for (int p = 0; p < 4; ++p) {
        float f0 = wf[grp * 8 + p * 2], f1 = wf[grp * 8 + p * 2 + 1];
        h[p] = pk2(f0, f1);
        if constexpr (SPLIT)
          l[p] = pk2(f0 - bf16f((unsigned short)(h[p] & 0xffff)),
                     f1 - bf16f((unsigned short)(h[p] >> 16)));
      }
      uint4 uh; uh.x = h[0]; uh.y = h[1]; uh.z = h[2]; uh.w = h[3];
      *(uint4*)&Wt[0][wn][wkg + grp * 8] = uh;
      if constexpr (SPLIT) {
        uint4 ul; ul.x = l[0]; ul.y = l[1]; ul.z = l[2]; ul.w = l[3];
        *(uint4*)&Wt[1][wn][wkg + grp * 8] = ul;
      }
    }
    __syncthreads();

#pragma unroll
    for (int ksub = 0; ksub < 2; ++ksub) {
      bf16x8 bh[2], bl[2];
#pragma unroll
      for (int rt = 0; rt < 2; ++rt) {
        bh[rt] = *(const bf16x8*)&As[0][wv * 32 + rt * 16 + c][ksub * 32 + g * 8];
        if constexpr (SPLIT)
          bl[rt] = *(const bf16x8*)&As[1][wv * 32 + rt * 16 + c][ksub * 32 + g * 8];
      }
#pragma unroll
      for (int ds = 0; ds < 4; ++ds) {
        bf16x8 ah_ = *(const bf16x8*)&Wt[0][ds * 16 + c][ksub * 32 + g * 8];
#pragma unroll
        for (int rt = 0; rt < 2; ++rt)
          acc[rt][ds] = __builtin_amdgcn_mfma_f32_16x16x32_bf16(ah_, bh[rt], acc[rt][ds], 0, 0, 0);
        if constexpr (SPLIT) {
          bf16x8 al_ = *(const bf16x8*)&Wt[1][ds * 16 + c][ksub * 32 + g * 8];
#pragma unroll
          for (int rt = 0; rt < 2; ++rt) {
            acc[rt][ds] = __builtin_amdgcn_mfma_f32_16x16x32_bf16(ah_, bl[rt], acc[rt][ds], 0, 0, 0);
            acc[rt][ds] = __builtin_amdgcn_mfma_f32_16x16x32_bf16(al_, bh[rt], acc[rt][ds], 0, 0, 0);
          }
        }
      }
    }
  }

#pragma unroll
  for (int rt = 0; rt < 2; ++rt) {
    const size_t m = (size_t)bm * 128 + wv * 32 + rt * 16 + c;
#pragma unroll
    for (int ds = 0; ds < 4; ++ds) {
      const int n = bn * 64 + ds * 16 + 4 * g;
      float4 bv = *(const float4*)&bias[n];
      float o0 = acc[rt][ds][0] + bv.x, o1 = acc[rt][ds][1] + bv.y;
      float o2 = acc[rt][ds][2] + bv.z, o3 = acc[rt][ds][3] + bv.w;
      if constexpr (OUTMODE == 1) {
        uint2 p; p.x = pk2(o0, o1); p.y = pk2(o2, o3);
        *(uint2*)((unsigned short*)Cv + m * D_ + n) = p;
      } else if constexpr (OUTMODE == 2) {
        // V^T: [b][n][s]; b = m>>11, s = m&2047 (block never crosses batch)
        const unsigned u01 = pk2(o0, o1), u23 = pk2(o2, o3);
        unsigned short* base =
            (unsigned short*)Cv + ((size_t)(m >> 11) * D_ + n) * (size_t)S_ + (m & 2047);
        base[0]      = (unsigned short)u01;
        base[S_]     = (unsigned short)(u01 >> 16);
        base[2 * S_] = (unsigned short)u23;
        base[3 * S_] = (unsigned short)(u23 >> 16);
      } else {
        float4 o; o.x = o0; o.y = o1; o.z = o2; o.w = o3;
        *(float4*)((float*)Cv + m * D_ + n) = o;
      }
    }
  }
}

// Phase A: kfk plain GEMM -> bf16 (blocks 0..511) + v GEMM -> V^T (512..1023).
// Both halves SPLIT=0 -> 27.6KB arena -> 4 blocks/CU co-resident.
__global__ __launch_bounds__(256) void gemm_pair_kernel(
    const float* __restrict__ key, const float* __restrict__ W_fk,
    const float* __restrict__ b_fk, void* __restrict__ kfk_bf16,
    const float* __restrict__ value, const float* __restrict__ W0,
    const float* __restrict__ b0, void* __restrict__ vT) {
  __shared__ __align__(16) char Lraw[27648];
  int bid = blockIdx.x;
  if (bid < 512) {
    gemm_body<0, 1>(key, W_fk, b_fk, kfk_bf16, bid & 7, bid >> 3, Lraw);
  } else {
    bid -= 512;
    gemm_body<0, 2>(value, W0, b0, vT, bid & 7, bid >> 3, Lraw);
  }
}

// Final: out = x @ Wout + bout (split precision: direct output).
__global__ __launch_bounds__(256) void gemm_out_kernel(
    const float* __restrict__ x, const float* __restrict__ Wout,
    const float* __restrict__ bout, float* __restrict__ out) {
  __shared__ __align__(16) char Lraw[55296];
  gemm_body<1, 0>(x, Wout, bout, out, blockIdx.x & 7, blockIdx.x >> 3, Lraw);
}

// ---------------------------------------------------------------------------
// Causal local-window (L=5) softmax pooling body; f32 or bf16 in, bf16 out.
// ---------------------------------------------------------------------------
template <int BF16IN>
static __device__ __forceinline__ void pool_body(
    const void* __restrict__ xv, unsigned short* __restrict__ out,
    float oscale, int bid) {
  const int gtid = bid * 256 + threadIdx.x;
  const int wave = gtid >> 6;
  const int lane = gtid & 63;
  const int b = wave / S_, s = wave % S_;
  const int d0 = lane * 8;
  float xi[8];
  float win[5][8];
  if constexpr (BF16IN) {
    const unsigned short* xrow =
        (const unsigned short*)xv + ((size_t)b * S_ + s) * D_ + d0;
    uint4 u = *(const uint4*)xrow;
#pragma unroll
    for (int t = 0; t < 4; ++t) {
      unsigned w_ = ((const unsigned*)&u)[t];
      xi[2 * t] = bf16f((unsigned short)(w_ & 0xffff));
      xi[2 * t + 1] = bf16f((unsigned short)(w_ >> 16));
    }
  } else {
    const float* xrow = (const float*)xv + ((size_t)b * S_ + s) * D_ + d0;
    *(float4*)&xi[0] = *(const float4*)xrow;
    *(float4*)&xi[4] = *(const float4*)(xrow + 4);
  }
  float sc[5];
#pragma unroll
  for (int j = 0; j < 5; ++j) {
    int src = s - 4 + j;
    float part = 0.f;
    if (src >= 0) {
      if constexpr (BF16IN) {
        const unsigned short* wr =
            (const unsigned short*)xv + ((size_t)b * S_ + src) * D_ + d0;
        uint4 u = *(const uint4*)wr;
#pragma unroll
        for (int t = 0; t < 4; ++t) {
          unsigned w_ = ((const unsigned*)&u)[t];
          win[j][2 * t] = bf16f((unsigned short)(w_ & 0xffff));
          win[j][2 * t + 1] = bf16f((unsigned short)(w_ >> 16));
        }
      } else {
        const float* wr = (const float*)xv + ((size_t)b * S_ + src) * D_ + d0;
        *(float4*)&win[j][0] = *(const float4*)wr;
        *(float4*)&win[j][4] = *(const float4*)(wr + 4);
      }
#pragma unroll
      for (int t = 0; t < 8; ++t) part += xi[t] * win[j][t];
    } else {
#pragma unroll
      for (int t = 0; t < 8; ++t) win[j][t] = 0.f;
    }
    sc[j] = part;
  }
#pragma unroll
  for (int off = 1; off < 64; off <<= 1) {
#pragma unroll
    for (int j = 0; j < 5; ++j) sc[j] += __shfl_xor(sc[j], off, 64);
  }
  const float scale = 0.04419417382415922f;  // 1/sqrt(512)
  float m = sc[0] * scale;
#pragma unroll
  for (int j = 1; j < 5; ++j) m = fmaxf(m, sc[j] * scale);
  float w[5], lsum = 0.f;
#pragma unroll
  for (int j = 0; j < 5; ++j) { w[j] = expf(sc[j] * scale - m); lsum += w[j]; }
  const float inv = oscale / lsum;
  float o[8] = {};
#pragma unroll
  for (int j = 0; j < 5; ++j)
#pragma unroll
    for (int t = 0; t < 8; ++t) o[t] += w[j] * win[j][t];
  unsigned short* orow = out + ((size_t)b * S_ + s) * D_;
  uint4 pk;
  pk.x = pk2(o[0] * inv, o[1] * inv);
  pk.y = pk2(o[2] * inv, o[3] * inv);
  pk.z = pk2(o[4] * inv, o[5] * inv);
  pk.w = pk2(o[6] * inv, o[7] * inv);
  *(uint4*)&orow[d0] = pk;
}

// Phase B: pool-k from bf16 kfk (blocks 0..2047) + pool-q from f32 query.
__global__ __launch_bounds__(256) void pool_pair_kernel(
    const unsigned short* __restrict__ kfk_bf16, unsigned short* __restrict__ kout,
    const float* __restrict__ query, unsigned short* __restrict__ qout,
    float qscale) {
  const int bid = blockIdx.x;
  if (bid < 2048) pool_body<1>(kfk_bf16, kout, 1.0f, bid);
  else            pool_body<0>(query, qout, qscale, bid - 2048);
}

// ---------------------------------------------------------------------------
// 32x32x16 MFMA flash attention, 2-way KV-split (unchanged from round 11).
// ---------------------------------------------------------------------------
__global__ __launch_bounds__(256, 3) void attn_mfma32_kernel(
    const unsigned short* __restrict__ q, const unsigned short* __restrict__ k,
    const unsigned short* __restrict__ vt, float* __restrict__ x) {
  const int bid = (blockIdx.x & 7) * 128 + (blockIdx.x >> 3);  // XCD swizzle
  const int qb = bid & 31;             // 64-row q-block
  const int h  = (bid >> 5) & 7;
  const int b  = bid >> 8;
  const int tid = threadIdx.x;
  const int w = tid >> 6, l = tid & 63;
  const int ql = l & 31, hi = l >> 5;
  const int wq = w & 1, wh = w >> 1;

  __shared__ __align__(16) unsigned short Kb[2][2][4096];  // [buf][half] 32KB
  __shared__ __align__(16) unsigned short Vb[2][4096];     // [half]     16KB

  bf16x8 Qf[4];
  {
    const unsigned short* qg =
        q + ((size_t)b * S_ + qb * 64 + wq * 32 + ql) * D_ + h * 64 + hi * 8;
#pragma unroll
    for (int f = 0; f < 4; ++f) Qf[f] = *(const bf16x8*)(qg + f * 16);
  }

  f32x16 accO[2] = {};           // O^T: [d-tile 32][q]
  float m = -INFINITY, lsum = 0.f;

  const int lr8 = l >> 3, lc = l & 7;
  const unsigned short* kg =
      k + ((size_t)b * S_ + wh * 1024 + wq * 32 + lr8) * D_ + h * 64 + ((lc ^ lr8) << 3);
  const unsigned short* vg =
      vt + ((size_t)b * D_ + h * 64 + wq * 32 + lr8) * (size_t)S_ + wh * 1024 + ((lc ^ lr8) << 3);

  auto ISSUE_K = [&](int t, int bf) {
    const unsigned short* kp = kg + (size_t)t * 64 * D_;
    char* dk = (char*)&Kb[bf][wh][0] + wq * 4096;
#pragma unroll
    for (int j = 0; j < 4; ++j)
      __builtin_amdgcn_global_load_lds((gu32*)(kp + (size_t)j * 8 * D_),
                                       (lu32*)(dk + j * 1024), 16, 0, 0);
  };
  auto ISSUE_V = [&](int t) {
    const unsigned short* vp = vg + t * 64;
    char* dv = (char*)&Vb[wh][0] + wq * 4096;
#pragma unroll
    for (int j = 0; j < 4; ++j)
      __builtin_amdgcn_global_load_lds((gu32*)(vp + (size_t)j * 8 * S_),
                                       (lu32*)(dv + j * 1024), 16, 0, 0);
  };

  // prologue: tile 0 K+V
  ISSUE_K(0, 0);
  ISSUE_V(0);
  asm volatile("s_waitcnt vmcnt(0)" ::: "memory");
  __builtin_amdgcn_s_barrier();
  __builtin_amdgcn_sched_barrier(0);

  int cur = 0;
  for (int kt = 0; kt < 16; ++kt) {
    const char* KsB = (const char*)&Kb[cur][wh][0];
    const char* VtB = (const char*)&Vb[wh][0];

    // ---- QK^T: two 32-key subtiles ----
    f32x16 sA = {}, sB = {};
    __builtin_amdgcn_s_setprio(1);
#pragma unroll
    for (int f = 0; f < 4; ++f) {
      bf16x8 a0 = *(const bf16x8*)(KsB + ((ql * 128 + f * 32 + hi * 16) ^ ((ql & 7) << 4)));
      bf16x8 a1 = *(const bf16x8*)(KsB + (((ql + 32) * 128 + f * 32 + hi * 16) ^ ((ql & 7) << 4)));
      sA = __builtin_amdgcn_mfma_f32_32x32x16_bf16(a0, Qf[f], sA, 0, 0, 0);
      sB = __builtin_amdgcn_mfma_f32_32x32x16_bf16(a1, Qf[f], sB, 0, 0, 0);
    }
    __builtin_amdgcn_s_setprio(0);

    if (kt + 1 < 16) ISSUE_K(kt + 1, cur ^ 1);   // lands under softmax+PV
    __builtin_amdgcn_sched_barrier(0);

    // ---- tree max, defer-max THR=10 ----
    float mx[8];
#pragma unroll
    for (int r = 0; r < 8; ++r)
      mx[r] = fmaxf(fmaxf(sA[r], sA[r + 8]), fmaxf(sB[r], sB[r + 8]));
    mx[0] = fmaxf(mx[0], mx[4]); mx[1] = fmaxf(mx[1], mx[5]);
    mx[2] = fmaxf(mx[2], mx[6]); mx[3] = fmaxf(mx[3], mx[7]);
    mx[0] = fmaxf(fmaxf(mx[0], mx[1]), fmaxf(mx[2], mx[3]));
    const float mt = fmaxf(mx[0], __shfl_xor(mx[0], 32, 64));
    if (!__all(mt <= m + 10.0f)) {
      const float mn = fmaxf(m, mt);
      const float corr = ex2(m - mn);
      m = mn;
      lsum *= corr;
#pragma unroll
      for (int dt = 0; dt < 2; ++dt)
#pragma unroll
        for (int r = 0; r < 16; ++r) accO[dt][r] *= corr;
    }

    // ---- fused exp2 -> pack -> pairwise sum ----
    unsigned WA[8], WB[8];
    float s0 = 0.f, s1 = 0.f, s2 = 0.f, s3 = 0.f;
#pragma unroll
    for (int t = 0; t < 4; ++t) {
      float a0 = ex2(sA[4 * t + 0] - m), a1 = ex2(sA[4 * t + 1] - m);
      float a2 = ex2(sA[4 * t + 2] - m), a3 = ex2(sA[4 * t + 3] - m);
      WA[2 * t] = pk2(a0, a1); WA[2 * t + 1] = pk2(a2, a3);
      s0 += a0 + a1; s1 += a2 + a3;
      float b0 = ex2(sB[4 * t + 0] - m), b1 = ex2(sB[4 * t + 1] - m);
      float b2 = ex2(sB[4 * t + 2] - m), b3 = ex2(sB[4 * t + 3] - m);
      WB[2 * t] = pk2(b0, b1); WB[2 * t + 1] = pk2(b2, b3);
      s2 += b0 + b1; s3 += b2 + b3;
    }
    lsum += (s0 + s1) + (s2 + s3);

    // ---- wait V(t) (counted: K(t+1) may stay in flight), make visible ----
    if (kt + 1 < 16) asm volatile("s_waitcnt vmcnt(4)" ::: "memory");
    else             asm volatile("s_waitcnt vmcnt(0)" ::: "memory");
    __builtin_amdgcn_s_barrier();
    __builtin_amdgcn_sched_barrier(0);

    // ---- PV: 4 key-chunks x 2 d-tiles ----
#pragma unroll
    for (int kc = 0; kc < 4; ++kc) {
      unsigned w0 = (kc < 2) ? WA[(kc & 1) * 4 + 0] : WB[(kc & 1) * 4 + 0];
      unsigned w1 = (kc < 2) ? WA[(kc & 1) * 4 + 1] : WB[(kc & 1) * 4 + 1];
      unsigned w2 = (kc < 2) ? WA[(kc & 1) * 4 + 2] : WB[(kc & 1) * 4 + 2];
      unsigned w3 = (kc < 2) ? WA[(kc & 1) * 4 + 3] : WB[(kc & 1) * 4 + 3];
      asm volatile("v_permlane32_swap_b32 %0, %1" : "+v"(w0), "+v"(w2));
      asm volatile("v_permlane32_swap_b32 %0, %1" : "+v"(w1), "+v"(w3));
      union { unsigned u[4]; bf16x8 v8; } pb;
      pb.u[0] = w0; pb.u[1] = w1; pb.u[2] = w2; pb.u[3] = w3;
      __builtin_amdgcn_s_setprio(1);
#pragma unroll
      for (int dt = 0; dt < 2; ++dt) {
        const int vrow = dt * 32 + ql;
        bf16x8 va = *(const bf16x8*)(VtB + ((vrow * 128 + kc * 32 + hi * 16) ^ ((ql & 7) << 4)));
        accO[dt] = __builtin_amdgcn_mfma_f32_32x32x16_bf16(va, pb.v8, accO[dt], 0, 0, 0);
      }
      __builtin_amdgcn_s_setprio(0);
    }

    // ---- V buffer recycle: all waves done reading, then refill ----
    __builtin_amdgcn_s_barrier();
    __builtin_amdgcn_sched_barrier(0);
    if (kt + 1 < 16) {
      ISSUE_V(kt + 1);
      asm volatile("s_waitcnt vmcnt(4)" ::: "memory");  // waits K(t+1); V(t+1) flies
      __builtin_amdgcn_s_barrier();
      __builtin_amdgcn_sched_barrier(0);
    }
    cur ^= 1;
  }

  // ---- cross-wave combine (halves share q-subtile); reuse Kb as scratch ----
  float lw = lsum + __shfl_xor(lsum, 32, 64);
  __syncthreads();                        // all waves done with tiles
  float* cb = (float*)Kb + (size_t)wq * 2176 + (size_t)l * 34;
  if (wh == 1) {
#pragma unroll
    for (int dt = 0; dt < 2; ++dt)
#pragma unroll
      for (int r = 0; r < 16; ++r) cb[dt * 16 + r] = accO[dt][r];
    cb[32] = m; cb[33] = lw;
  }
  __syncthreads();
  if (wh == 0) {
    const float m1 = cb[32], l1 = cb[33];
    const float mn = fmaxf(m, m1);
    const float a0 = ex2(m - mn), a1 = ex2(m1 - mn);
    const float inv = 1.f / (lw * a0 + l1 * a1);
    float* xrow = x + ((size_t)b * S_ + qb * 64 + wq * 32 + ql) * D_ + h * 64;
#pragma unroll
    for (int dt = 0; dt < 2; ++dt)
#pragma unroll
      for (int g0 = 0; g0 < 4; ++g0) {
        float4 o;
        o.x = (accO[dt][4 * g0 + 0] * a0 + cb[dt * 16 + 4 * g0 + 0] * a1) * inv;
        o.y = (accO[dt][4 * g0 + 1] * a0 + cb[dt * 16 + 4 * g0 + 1] * a1) * inv;
        o.z = (accO[dt][4 * g0 + 2] * a0 + cb[dt * 16 + 4 * g0 + 2] * a1) * inv;
        o.w = (accO[dt][4 * g0 + 3] * a0 + cb[dt * 16 + 4 * g0 + 3] * a1) * inv;
        *(float4*)&xrow[dt * 32 + hi * 4 + g0 * 8] = o;
      }
  }
}

// ---------------------------------------------------------------------------
extern "C" void kernel_launch(void* const* d_in, const int* in_sizes, int n_in,
                              void* d_out, int out_size, void* d_ws, size_t ws_size,
                              hipStream_t stream) {
  const float* query = (const float*)d_in[0];
  const float* key   = (const float*)d_in[1];
  const float* value = (const float*)d_in[2];
  const float* W_fk = (const float*)d_in[4];
  const float* b_fk = (const float*)d_in[5];
  const float* W0   = (const float*)d_in[6];
  const float* b0   = (const float*)d_in[7];
  const float* Wout = (const float*)d_in[8];
  const float* bout = (const float*)d_in[9];
  float* out = (float*)d_out;

  char* ws = (char*)d_ws;
  unsigned short* kfk_bf16 = (unsigned short*)ws;                // 8MB @ 0
  float* x_f32   = (float*)(ws + (16u << 20));                   // 16MB @ 16MB
  unsigned short* k_bf16  = (unsigned short*)(ws + (32u << 20)); // 8MB @ 32MB
  unsigned short* vT_bf16 = (unsigned short*)(ws + (40u << 20)); // 8MB @ 40MB, [b][d][s]
  unsigned short* q_bf16  = (unsigned short*)(ws + (48u << 20)); // 8MB @ 48MB

  // 1/sqrt(dk) * log2(e): softmax runs in exp2 domain
  const float qscale = 0.125f * 1.4426950408889634f;

  // A: kfk = key@W_fk+b_fk (bf16)  ||  vT = (value@W0+b0)^T (bf16)
  gemm_pair_kernel<<<1024, 256, 0, stream>>>(key, W_fk, b_fk, kfk_bf16,
                                             value, W0, b0, vT_bf16);
  // B: k = pool(kfk_bf16) -> bf16  ||  q = pool(query)*qscale -> bf16
  pool_pair_kernel<<<4096, 256, 0, stream>>>(kfk_bf16, k_bf16, query, q_bf16, qscale);
  // C: attention -> f32
  attn_mfma32_kernel<<<dim3(B_ * H_ * (S_ / 64)), 256, 0, stream>>>(
      q_bf16, k_bf16, vT_bf16, x_f32);
  // D: out = x @ Wout + bout (split)
  gemm_out_kernel<<<512, 256, 0, stream>>>(x_f32, Wout, bout, out);
}

// Round 13
// 150.300 us; speedup vs baseline: 1.4884x; 1.0403x over previous
//
#include <hip/hip_runtime.h>
#include <hip/hip_bf16.h>
#include <math.h>

#define B_  4
#define S_  2048
#define D_  512
#define H_  8
#define DK_ 64
#define BS_ (B_*S_)

using bf16x8 = __attribute__((ext_vector_type(8))) short;
using f32x4  = __attribute__((ext_vector_type(4))) float;
using f32x16 = __attribute__((ext_vector_type(16))) float;

typedef const __attribute__((address_space(1))) unsigned int gu32;
typedef __attribute__((address_space(3))) unsigned int lu32;

static __device__ inline float bf16f(unsigned short u) {
  union { unsigned u32; float f; } x; x.u32 = (unsigned)u << 16; return x.f;
}
// HW packed f32->bf16 (RNE), 1 VALU op for 2 values
static __device__ inline unsigned pk2(float a, float b) {
  unsigned r;
  asm("v_cvt_pk_bf16_f32 %0, %1, %2" : "=v"(r) : "v"(a), "v"(b));
  return r;
}
static __device__ inline float ex2(float a) {
  return __builtin_amdgcn_exp2f(a);   // raw v_exp_f32
}

// ---------------------------------------------------------------------------
// GEMM body with register-prefetch pipeline: tile t+1's global loads issue
// right after the LDS-write barrier and land during tile t's MFMAs; they are
// only waited at the NEXT iteration's STORET. Math identical to round 12.
// OUTMODE: 0 = f32 row-major, 1 = bf16 row-major, 2 = bf16 V^T [b][n][s].
// ---------------------------------------------------------------------------
template <int SPLIT, int OUTMODE>
static __device__ __forceinline__ void gemm_body(
    const float* __restrict__ A, const float* __restrict__ W,
    const float* __restrict__ bias, void* __restrict__ Cv,
    int bn, int bm, char* lds) {
  unsigned short (*As)[128][72] = (unsigned short(*)[128][72])lds;
  unsigned short (*Wt)[64][72] =
      (unsigned short(*)[64][72])(lds + (size_t)(SPLIT + 1) * 128 * 72 * 2);
  const int tid = threadIdx.x;
  const int wv = tid >> 6, lane = tid & 63;
  const int c = lane & 15, g = lane >> 4;

  f32x4 acc[2][4];
#pragma unroll
  for (int rt = 0; rt < 2; ++rt)
#pragma unroll
    for (int ds = 0; ds < 4; ++ds) acc[rt][ds] = f32x4{0.f, 0.f, 0.f, 0.f};

  const int arow = tid >> 1, ah = (tid & 1) * 32;
  const int wn = tid & 63, wkg = (tid >> 6) * 16;

  float af[32];   // prefetched A rows (f32)
  float wf[16];   // prefetched W column-slices (f32)

  auto LOADT = [&](int k0) {
    const float* ag = A + ((size_t)(bm * 128 + arow)) * D_ + k0 + ah;
#pragma unroll
    for (int i = 0; i < 8; ++i) *(float4*)&af[i * 4] = *(const float4*)(ag + i * 4);
    const float* wg = W + (size_t)(k0 + wkg) * D_ + bn * 64 + wn;
#pragma unroll
    for (int i = 0; i < 16; ++i) wf[i] = wg[(size_t)i * D_];
  };

  auto STORET = [&]() {
#pragma unroll
    for (int grp = 0; grp < 4; ++grp) {
      unsigned h[4], l[4];
#pragma unroll
      for (int p = 0; p < 4; ++p) {
        float f0 = af[grp * 8 + p * 2], f1 = af[grp * 8 + p * 2 + 1];
        h[p] = pk2(f0, f1);
        if constexpr (SPLIT)
          l[p] = pk2(f0 - bf16f((unsigned short)(h[p] & 0xffff)),
                     f1 - bf16f((unsigned short)(h[p] >> 16)));
      }
      uint4 uh; uh.x = h[0]; uh.y = h[1]; uh.z = h[2]; uh.w = h[3];
      *(uint4*)&As[0][arow][ah + grp * 8] = uh;
      if constexpr (SPLIT) {
        uint4 ul; ul.x = l[0]; ul.y = l[1]; ul.z = l[2]; ul.w = l[3];
        *(uint4*)&As[1][arow][ah + grp * 8] = ul;
      }
    }
#pragma unroll
    for (int grp = 0; grp < 2; ++grp) {
      unsigned h[4], l[4];
#pragma unroll
      for (int p = 0; p < 4; ++p) {
        float f0 = wf[grp * 8 + p * 2], f1 = wf[grp * 8 + p * 2 + 1];
        h[p] = pk2(f0, f1);
        if constexpr (SPLIT)
          l[p] = pk2(f0 - bf16f((unsigned short)(h[p] & 0xffff)),
                     f1 - bf16f((unsigned short)(h[p] >> 16)));
      }
      uint4 uh; uh.x = h[0]; uh.y = h[1]; uh.z = h[2]; uh.w = h[3];
      *(uint4*)&Wt[0][wn][wkg + grp * 8] = uh;
      if constexpr (SPLIT) {
        uint4 ul; ul.x = l[0]; ul.y = l[1]; ul.z = l[2]; ul.w = l[3];
        *(uint4*)&Wt[1][wn][wkg + grp * 8] = ul;
      }
    }
  };

  LOADT(0);
  for (int k0 = 0; k0 < D_; k0 += 64) {
    __syncthreads();        // prev MFMA done reading LDS
    STORET();               // waits the prefetched loads, packs, writes LDS
    __syncthreads();
    if (k0 + 64 < D_) LOADT(k0 + 64);   // flies under the MFMAs below

#pragma unroll
    for (int ksub = 0; ksub < 2; ++ksub) {
      bf16x8 bh[2], bl[2];
#pragma unroll
      for (int rt = 0; rt < 2; ++rt) {
        bh[rt] = *(const bf16x8*)&As[0][wv * 32 + rt * 16 + c][ksub * 32 + g * 8];
        if constexpr (SPLIT)
          bl[rt] = *(const bf16x8*)&As[1][wv * 32 + rt * 16 + c][ksub * 32 + g * 8];
      }
#pragma unroll
      for (int ds = 0; ds < 4; ++ds) {
        bf16x8 ah_ = *(const bf16x8*)&Wt[0][ds * 16 + c][ksub * 32 + g * 8];
#pragma unroll
        for (int rt = 0; rt < 2; ++rt)
          acc[rt][ds] = __builtin_amdgcn_mfma_f32_16x16x32_bf16(ah_, bh[rt], acc[rt][ds], 0, 0, 0);
        if constexpr (SPLIT) {
          bf16x8 al_ = *(const bf16x8*)&Wt[1][ds * 16 + c][ksub * 32 + g * 8];
#pragma unroll
          for (int rt = 0; rt < 2; ++rt) {
            acc[rt][ds] = __builtin_amdgcn_mfma_f32_16x16x32_bf16(ah_, bl[rt], acc[rt][ds], 0, 0, 0);
            acc[rt][ds] = __builtin_amdgcn_mfma_f32_16x16x32_bf16(al_, bh[rt], acc[rt][ds], 0, 0, 0);
          }
        }
      }
    }
  }

#pragma unroll
  for (int rt = 0; rt < 2; ++rt) {
    const size_t m = (size_t)bm * 128 + wv * 32 + rt * 16 + c;
#pragma unroll
    for (int ds = 0; ds < 4; ++ds) {
      const int n = bn * 64 + ds * 16 + 4 * g;
      float4 bv = *(const float4*)&bias[n];
      float o0 = acc[rt][ds][0] + bv.x, o1 = acc[rt][ds][1] + bv.y;
      float o2 = acc[rt][ds][2] + bv.z, o3 = acc[rt][ds][3] + bv.w;
      if constexpr (OUTMODE == 1) {
        uint2 p; p.x = pk2(o0, o1); p.y = pk2(o2, o3);
        *(uint2*)((unsigned short*)Cv + m * D_ + n) = p;
      } else if constexpr (OUTMODE == 2) {
        // V^T: [b][n][s]; b = m>>11, s = m&2047 (block never crosses batch)
        const unsigned u01 = pk2(o0, o1), u23 = pk2(o2, o3);
        unsigned short* base =
            (unsigned short*)Cv + ((size_t)(m >> 11) * D_ + n) * (size_t)S_ + (m & 2047);
        base[0]      = (unsigned short)u01;
        base[S_]     = (unsigned short)(u01 >> 16);
        base[2 * S_] = (unsigned short)u23;
        base[3 * S_] = (unsigned short)(u23 >> 16);
      } else {
        float4 o; o.x = o0; o.y = o1; o.z = o2; o.w = o3;
        *(float4*)((float*)Cv + m * D_ + n) = o;
      }
    }
  }
}

// ---------------------------------------------------------------------------
// Causal local-window (L=5) softmax pooling body; f32 or bf16 in, bf16 out.
// ---------------------------------------------------------------------------
template <int BF16IN>
static __device__ __forceinline__ void pool_body(
    const void* __restrict__ xv, unsigned short* __restrict__ out,
    float oscale, int bid) {
  const int gtid = bid * 256 + threadIdx.x;
  const int wave = gtid >> 6;
  const int lane = gtid & 63;
  const int b = wave / S_, s = wave % S_;
  const int d0 = lane * 8;
  float xi[8];
  float win[5][8];
  if constexpr (BF16IN) {
    const unsigned short* xrow =
        (const unsigned short*)xv + ((size_t)b * S_ + s) * D_ + d0;
    uint4 u = *(const uint4*)xrow;
#pragma unroll
    for (int t = 0; t < 4; ++t) {
      unsigned w_ = ((const unsigned*)&u)[t];
      xi[2 * t] = bf16f((unsigned short)(w_ & 0xffff));
      xi[2 * t + 1] = bf16f((unsigned short)(w_ >> 16));
    }
  } else {
    const float* xrow = (const float*)xv + ((size_t)b * S_ + s) * D_ + d0;
    *(float4*)&xi[0] = *(const float4*)xrow;
    *(float4*)&xi[4] = *(const float4*)(xrow + 4);
  }
  float sc[5];
#pragma unroll
  for (int j = 0; j < 5; ++j) {
    int src = s - 4 + j;
    float part = 0.f;
    if (src >= 0) {
      if constexpr (BF16IN) {
        const unsigned short* wr =
            (const unsigned short*)xv + ((size_t)b * S_ + src) * D_ + d0;
        uint4 u = *(const uint4*)wr;
#pragma unroll
        for (int t = 0; t < 4; ++t) {
          unsigned w_ = ((const unsigned*)&u)[t];
          win[j][2 * t] = bf16f((unsigned short)(w_ & 0xffff));
          win[j][2 * t + 1] = bf16f((unsigned short)(w_ >> 16));
        }
      } else {
        const float* wr = (const float*)xv + ((size_t)b * S_ + src) * D_ + d0;
        *(float4*)&win[j][0] = *(const float4*)wr;
        *(float4*)&win[j][4] = *(const float4*)(wr + 4);
      }
#pragma unroll
      for (int t = 0; t < 8; ++t) part += xi[t] * win[j][t];
    } else {
#pragma unroll
      for (int t = 0; t < 8; ++t) win[j][t] = 0.f;
    }
    sc[j] = part;
  }
#pragma unroll
  for (int off = 1; off < 64; off <<= 1) {
#pragma unroll
    for (int j = 0; j < 5; ++j) sc[j] += __shfl_xor(sc[j], off, 64);
  }
  const float scale = 0.04419417382415922f;  // 1/sqrt(512)
  float m = sc[0] * scale;
#pragma unroll
  for (int j = 1; j < 5; ++j) m = fmaxf(m, sc[j] * scale);
  float w[5], lsum = 0.f;
#pragma unroll
  for (int j = 0; j < 5; ++j) { w[j] = expf(sc[j] * scale - m); lsum += w[j]; }
  const float inv = oscale / lsum;
  float o[8] = {};
#pragma unroll
  for (int j = 0; j < 5; ++j)
#pragma unroll
    for (int t = 0; t < 8; ++t) o[t] += w[j] * win[j][t];
  unsigned short* orow = out + ((size_t)b * S_ + s) * D_;
  uint4 pk;
  pk.x = pk2(o[0] * inv, o[1] * inv);
  pk.y = pk2(o[2] * inv, o[3] * inv);
  pk.z = pk2(o[4] * inv, o[5] * inv);
  pk.w = pk2(o[6] * inv, o[7] * inv);
  *(uint4*)&orow[d0] = pk;
}

// ---------------------------------------------------------------------------
// Phase A (grid 3072): kfk plain GEMM -> bf16 (blocks 0..511), v GEMM -> V^T
// (512..1023), pool-q from query (1024..3071, independent of the GEMMs —
// pure-memory blocks overlap the GEMM compute phase).
// ---------------------------------------------------------------------------
__global__ __launch_bounds__(256) void phaseA_kernel(
    const float* __restrict__ key, const float* __restrict__ W_fk,
    const float* __restrict__ b_fk, void* __restrict__ kfk_bf16,
    const float* __restrict__ value, const float* __restrict__ W0,
    const float* __restrict__ b0, void* __restrict__ vT,
    const float* __restrict__ query, unsigned short* __restrict__ qout,
    float qscale) {
  __shared__ __align__(16) char Lraw[27648];
  int bid = blockIdx.x;
  if (bid < 512) {
    gemm_body<0, 1>(key, W_fk, b_fk, kfk_bf16, bid & 7, bid >> 3, Lraw);
  } else if (bid < 1024) {
    bid -= 512;
    gemm_body<0, 2>(value, W0, b0, vT, bid & 7, bid >> 3, Lraw);
  } else {
    pool_body<0>(query, qout, qscale, bid - 1024);
  }
}

// Phase B: pool-k from bf16 kfk (2048 blocks).
__global__ __launch_bounds__(256) void pool_k_kernel(
    const unsigned short* __restrict__ kfk_bf16,
    unsigned short* __restrict__ kout) {
  pool_body<1>(kfk_bf16, kout, 1.0f, blockIdx.x);
}

// Final: out = x @ Wout + bout (split precision, register-prefetch).
__global__ __launch_bounds__(256) void gemm_out_kernel(
    const float* __restrict__ x, const float* __restrict__ Wout,
    const float* __restrict__ bout, float* __restrict__ out) {
  __shared__ __align__(16) char Lraw[55296];
  gemm_body<1, 0>(x, Wout, bout, out, blockIdx.x & 7, blockIdx.x >> 3, Lraw);
}

// ---------------------------------------------------------------------------
// 32x32x16 MFMA flash attention, 2-way KV-split (unchanged from round 12).
// ---------------------------------------------------------------------------
__global__ __launch_bounds__(256, 3) void attn_mfma32_kernel(
    const unsigned short* __restrict__ q, const unsigned short* __restrict__ k,
    const unsigned short* __restrict__ vt, float* __restrict__ x) {
  const int bid = (blockIdx.x & 7) * 128 + (blockIdx.x >> 3);  // XCD swizzle
  const int qb = bid & 31;             // 64-row q-block
  const int h  = (bid >> 5) & 7;
  const int b  = bid >> 8;
  const int tid = threadIdx.x;
  const int w = tid >> 6, l = tid & 63;
  const int ql = l & 31, hi = l >> 5;
  const int wq = w & 1, wh = w >> 1;

  __shared__ __align__(16) unsigned short Kb[2][2][4096];  // [buf][half] 32KB
  __shared__ __align__(16) unsigned short Vb[2][4096];     // [half]     16KB

  bf16x8 Qf[4];
  {
    const unsigned short* qg =
        q + ((size_t)b * S_ + qb * 64 + wq * 32 + ql) * D_ + h * 64 + hi * 8;
#pragma unroll
    for (int f = 0; f < 4; ++f) Qf[f] = *(const bf16x8*)(qg + f * 16);
  }

  f32x16 accO[2] = {};           // O^T: [d-tile 32][q]
  float m = -INFINITY, lsum = 0.f;

  const int lr8 = l >> 3, lc = l & 7;
  const unsigned short* kg =
      k + ((size_t)b * S_ + wh * 1024 + wq * 32 + lr8) * D_ + h * 64 + ((lc ^ lr8) << 3);
  const unsigned short* vg =
      vt + ((size_t)b * D_ + h * 64 + wq * 32 + lr8) * (size_t)S_ + wh * 1024 + ((lc ^ lr8) << 3);

  auto ISSUE_K = [&](int t, int bf) {
    const unsigned short* kp = kg + (size_t)t * 64 * D_;
    char* dk = (char*)&Kb[bf][wh][0] + wq * 4096;
#pragma unroll
    for (int j = 0; j < 4; ++j)
      __builtin_amdgcn_global_load_lds((gu32*)(kp + (size_t)j * 8 * D_),
                                       (lu32*)(dk + j * 1024), 16, 0, 0);
  };
  auto ISSUE_V = [&](int t) {
    const unsigned short* vp = vg + t * 64;
    char* dv = (char*)&Vb[wh][0] + wq * 4096;
#pragma unroll
    for (int j = 0; j < 4; ++j)
      __builtin_amdgcn_global_load_lds((gu32*)(vp + (size_t)j * 8 * S_),
                                       (lu32*)(dv + j * 1024), 16, 0, 0);
  };

  // prologue: tile 0 K+V
  ISSUE_K(0, 0);
  ISSUE_V(0);
  asm volatile("s_waitcnt vmcnt(0)" ::: "memory");
  __builtin_amdgcn_s_barrier();
  __builtin_amdgcn_sched_barrier(0);

  int cur = 0;
  for (int kt = 0; kt < 16; ++kt) {
    const char* KsB = (const char*)&Kb[cur][wh][0];
    const char* VtB = (const char*)&Vb[wh][0];

    // ---- QK^T: two 32-key subtiles ----
    f32x16 sA = {}, sB = {};
    __builtin_amdgcn_s_setprio(1);
#pragma unroll
    for (int f = 0; f < 4; ++f) {
      bf16x8 a0 = *(const bf16x8*)(KsB + ((ql * 128 + f * 32 + hi * 16) ^ ((ql & 7) << 4)));
      bf16x8 a1 = *(const bf16x8*)(KsB + (((ql + 32) * 128 + f * 32 + hi * 16) ^ ((ql & 7) << 4)));
      sA = __builtin_amdgcn_mfma_f32_32x32x16_bf16(a0, Qf[f], sA, 0, 0, 0);
      sB = __builtin_amdgcn_mfma_f32_32x32x16_bf16(a1, Qf[f], sB, 0, 0, 0);
    }
    __builtin_amdgcn_s_setprio(0);

    if (kt + 1 < 16) ISSUE_K(kt + 1, cur ^ 1);   // lands under softmax+PV
    __builtin_amdgcn_sched_barrier(0);

    // ---- tree max, defer-max THR=10 ----
    float mx[8];
#pragma unroll
    for (int r = 0; r < 8; ++r)
      mx[r] = fmaxf(fmaxf(sA[r], sA[r + 8]), fmaxf(sB[r], sB[r + 8]));
    mx[0] = fmaxf(mx[0], mx[4]); mx[1] = fmaxf(mx[1], mx[5]);
    mx[2] = fmaxf(mx[2], mx[6]); mx[3] = fmaxf(mx[3], mx[7]);
    mx[0] = fmaxf(fmaxf(mx[0], mx[1]), fmaxf(mx[2], mx[3]));
    const float mt = fmaxf(mx[0], __shfl_xor(mx[0], 32, 64));
    if (!__all(mt <= m + 10.0f)) {
      const float mn = fmaxf(m, mt);
      const float corr = ex2(m - mn);
      m = mn;
      lsum *= corr;
#pragma unroll
      for (int dt = 0; dt < 2; ++dt)
#pragma unroll
        for (int r = 0; r < 16; ++r) accO[dt][r] *= corr;
    }

    // ---- fused exp2 -> pack -> pairwise sum ----
    unsigned WA[8], WB[8];
    float s0 = 0.f, s1 = 0.f, s2 = 0.f, s3 = 0.f;
#pragma unroll
    for (int t = 0; t < 4; ++t) {
      float a0 = ex2(sA[4 * t + 0] - m), a1 = ex2(sA[4 * t + 1] - m);
      float a2 = ex2(sA[4 * t + 2] - m), a3 = ex2(sA[4 * t + 3] - m);
      WA[2 * t] = pk2(a0, a1); WA[2 * t + 1] = pk2(a2, a3);
      s0 += a0 + a1; s1 += a2 + a3;
      float b0 = ex2(sB[4 * t + 0] - m), b1 = ex2(sB[4 * t + 1] - m);
      float b2 = ex2(sB[4 * t + 2] - m), b3 = ex2(sB[4 * t + 3] - m);
      WB[2 * t] = pk2(b0, b1); WB[2 * t + 1] = pk2(b2, b3);
      s2 += b0 + b1; s3 += b2 + b3;
    }
    lsum += (s0 + s1) + (s2 + s3);

    // ---- wait V(t) (counted: K(t+1) may stay in flight), make visible ----
    if (kt + 1 < 16) asm volatile("s_waitcnt vmcnt(4)" ::: "memory");
    else             asm volatile("s_waitcnt vmcnt(0)" ::: "memory");
    __builtin_amdgcn_s_barrier();
    __builtin_amdgcn_sched_barrier(0);

    // ---- PV: 4 key-chunks x 2 d-tiles ----
#pragma unroll
    for (int kc = 0; kc < 4; ++kc) {
      unsigned w0 = (kc < 2) ? WA[(kc & 1) * 4 + 0] : WB[(kc & 1) * 4 + 0];
      unsigned w1 = (kc < 2) ? WA[(kc & 1) * 4 + 1] : WB[(kc & 1) * 4 + 1];
      unsigned w2 = (kc < 2) ? WA[(kc & 1) * 4 + 2] : WB[(kc & 1) * 4 + 2];
      unsigned w3 = (kc < 2) ? WA[(kc & 1) * 4 + 3] : WB[(kc & 1) * 4 + 3];
      asm volatile("v_permlane32_swap_b32 %0, %1" : "+v"(w0), "+v"(w2));
      asm volatile("v_permlane32_swap_b32 %0, %1" : "+v"(w1), "+v"(w3));
      union { unsigned u[4]; bf16x8 v8; } pb;
      pb.u[0] = w0; pb.u[1] = w1; pb.u[2] = w2; pb.u[3] = w3;
      __builtin_amdgcn_s_setprio(1);
#pragma unroll
      for (int dt = 0; dt < 2; ++dt) {
        const int vrow = dt * 32 + ql;
        bf16x8 va = *(const bf16x8*)(VtB + ((vrow * 128 + kc * 32 + hi * 16) ^ ((ql & 7) << 4)));
        accO[dt] = __builtin_amdgcn_mfma_f32_32x32x16_bf16(va, pb.v8, accO[dt], 0, 0, 0);
      }
      __builtin_amdgcn_s_setprio(0);
    }

    // ---- V buffer recycle: all waves done reading, then refill ----
    __builtin_amdgcn_s_barrier();
    __builtin_amdgcn_sched_barrier(0);
    if (kt + 1 < 16) {
      ISSUE_V(kt + 1);
      asm volatile("s_waitcnt vmcnt(4)" ::: "memory");  // waits K(t+1); V(t+1) flies
      __builtin_amdgcn_s_barrier();
      __builtin_amdgcn_sched_barrier(0);
    }
    cur ^= 1;
  }

  // ---- cross-wave combine (halves share q-subtile); reuse Kb as scratch ----
  float lw = lsum + __shfl_xor(lsum, 32, 64);
  __syncthreads();                        // all waves done with tiles
  float* cb = (float*)Kb + (size_t)wq * 2176 + (size_t)l * 34;
  if (wh == 1) {
#pragma unroll
    for (int dt = 0; dt < 2; ++dt)
#pragma unroll
      for (int r = 0; r < 16; ++r) cb[dt * 16 + r] = accO[dt][r];
    cb[32] = m; cb[33] = lw;
  }
  __syncthreads();
  if (wh == 0) {
    const float m1 = cb[32], l1 = cb[33];
    const float mn = fmaxf(m, m1);
    const float a0 = ex2(m - mn), a1 = ex2(m1 - mn);
    const float inv = 1.f / (lw * a0 + l1 * a1);
    float* xrow = x + ((size_t)b * S_ + qb * 64 + wq * 32 + ql) * D_ + h * 64;
#pragma unroll
    for (int dt = 0; dt < 2; ++dt)
#pragma unroll
      for (int g0 = 0; g0 < 4; ++g0) {
        float4 o;
        o.x = (accO[dt][4 * g0 + 0] * a0 + cb[dt * 16 + 4 * g0 + 0] * a1) * inv;
        o.y = (accO[dt][4 * g0 + 1] * a0 + cb[dt * 16 + 4 * g0 + 1] * a1) * inv;
        o.z = (accO[dt][4 * g0 + 2] * a0 + cb[dt * 16 + 4 * g0 + 2] * a1) * inv;
        o.w = (accO[dt][4 * g0 + 3] * a0 + cb[dt * 16 + 4 * g0 + 3] * a1) * inv;
        *(float4*)&xrow[dt * 32 + hi * 4 + g0 * 8] = o;
      }
  }
}

// ---------------------------------------------------------------------------
extern "C" void kernel_launch(void* const* d_in, const int* in_sizes, int n_in,
                              void* d_out, int out_size, void* d_ws, size_t ws_size,
                              hipStream_t stream) {
  const float* query = (const float*)d_in[0];
  const float* key   = (const float*)d_in[1];
  const float* value = (const float*)d_in[2];
  const float* W_fk = (const float*)d_in[4];
  const float* b_fk = (const float*)d_in[5];
  const float* W0   = (const float*)d_in[6];
  const float* b0   = (const float*)d_in[7];
  const float* Wout = (const float*)d_in[8];
  const float* bout = (const float*)d_in[9];
  float* out = (float*)d_out;

  char* ws = (char*)d_ws;
  unsigned short* kfk_bf16 = (unsigned short*)ws;                // 8MB @ 0
  float* x_f32   = (float*)(ws + (16u << 20));                   // 16MB @ 16MB
  unsigned short* k_bf16  = (unsigned short*)(ws + (32u << 20)); // 8MB @ 32MB
  unsigned short* vT_bf16 = (unsigned short*)(ws + (40u << 20)); // 8MB @ 40MB, [b][d][s]
  unsigned short* q_bf16  = (unsigned short*)(ws + (48u << 20)); // 8MB @ 48MB

  // 1/sqrt(dk) * log2(e): softmax runs in exp2 domain
  const float qscale = 0.125f * 1.4426950408889634f;

  // A: kfk GEMM || v GEMM -> V^T || pool-q (independent, overlapped)
  phaseA_kernel<<<3072, 256, 0, stream>>>(key, W_fk, b_fk, kfk_bf16,
                                          value, W0, b0, vT_bf16,
                                          query, q_bf16, qscale);
  // B: k = pool(kfk_bf16)
  pool_k_kernel<<<2048, 256, 0, stream>>>(kfk_bf16, k_bf16);
  // C: attention -> f32
  attn_mfma32_kernel<<<dim3(B_ * H_ * (S_ / 64)), 256, 0, stream>>>(
      q_bf16, k_bf16, vT_bf16, x_f32);
  // D: out = x @ Wout + bout (split)
  gemm_out_kernel<<<512, 256, 0, stream>>>(x_f32, Wout, bout, out);
}